// Round 6
// baseline (230.379 us; speedup 1.0000x reference)
//
#include <hip/hip_runtime.h>
#include <cstdint>
#include <cmath>

// ---------------------------------------------------------------------------
// GProjection: project B*N points into V=3 views, bilinear-sample 3 feature
// pyramids (64@56x56, 128@28x28, 256@14x14 -> 448 ch), reduce max/mean/std
// over views. Output [B,N,3+3*448] f32.
//
// R6 = R5 code, MEASUREMENT ROUND: gproj_main_kernel launched TWICE in the
// full path (idempotent, identical writes). M = dur_R6 - dur_R5 isolates the
// main kernel's (L2-warm) duration, deciding whether to attack the main
// kernel (stores/gathers) or the fixed pipeline overhead next.
// ---------------------------------------------------------------------------

typedef float f32x2 __attribute__((ext_vector_type(2)));
typedef float f32x4 __attribute__((ext_vector_type(4)));
typedef _Float16 f16;
typedef _Float16 f16x2 __attribute__((ext_vector_type(2)));
typedef _Float16 f16x4 __attribute__((ext_vector_type(4)));

__global__ void setup_cams_kernel(const float* __restrict__ poses,
                                  const int* __restrict__ resolution,
                                  float* __restrict__ ws, int BV) {
    int t = blockIdx.x * blockDim.x + threadIdx.x;
    if (t == 0) {
        float h0 = ((float)resolution[0] - 1.0f) * 0.5f;
        float h1 = ((float)resolution[1] - 1.0f) * 0.5f;
        ws[0] = 111.5f - h0;   // c_off0
        ws[1] = 111.5f - h1;   // c_off1
        ws[2] = h0;            // half_res0
        ws[3] = h1;            // half_res1
    }
    if (t < BV) {
        const float* p = poses + (size_t)t * 5;
        const float d = 0.017453292519943295f;  // pi/180
        float theta = p[0] * d;
        float elr   = p[1] * d;
        float dist  = p[3];
        float st = sinf(theta), ct = cosf(theta);
        float se = sinf(elr),   ce = cosf(elr);
        float camy = dist * se;
        float lens = dist * ce;
        float camx = lens * ct;
        float camz = lens * st;
        float Zx = camx, Zy = camy, Zz = camz;
        float Yx = -camy * ct, Yy = lens, Yz = -camy * st;  // cos/sin(theta+pi)
        float Xx = Yy * Zz - Yz * Zy;
        float Xy = Yz * Zx - Yx * Zz;
        float Xz = Yx * Zy - Yy * Zx;
        float rx = 1.0f / sqrtf(Xx*Xx + Xy*Xy + Xz*Xz);
        float ry = 1.0f / sqrtf(Yx*Yx + Yy*Yy + Yz*Yz);
        float rz = 1.0f / sqrtf(Zx*Zx + Zy*Zy + Zz*Zz);
        float* c = ws + 4 + (size_t)t * 12;
        c[0] = Xx*rx; c[1] = Xy*rx; c[2] = Xz*rx;
        c[3] = Yx*ry; c[4] = Yy*ry; c[5] = Yz*ry;
        c[6] = Zx*rz; c[7] = Zy*rz; c[8] = Zz*rz;
        c[9] = camx; c[10] = camy; c[11] = camz;
    }
}

// ---- merged transpose: [C][P] f32 -> [P][C] f16, all 3 levels, one grid ----
__global__ void transpose_all_kernel(const float* __restrict__ f0,
                                     const float* __restrict__ f1,
                                     const float* __restrict__ f2,
                                     f16* __restrict__ t0, f16* __restrict__ t1,
                                     f16* __restrict__ t2, int BV) {
    __shared__ float tile[32][33];
    const int nb0 = 98 * 2 * BV;   // P=3136 -> 98 tiles, C=64 -> 2 tiles
    const int nb1 = 25 * 4 * BV;   // P=784  -> 25,      C=128 -> 4
    int bid = blockIdx.x;
    const float* src; f16* dst; int C, P, tP, local;
    if (bid < nb0)            { src = f0; dst = t0; C = 64;  P = 3136; tP = 98; local = bid; }
    else if (bid < nb0 + nb1) { src = f1; dst = t1; C = 128; P = 784;  tP = 25; local = bid - nb0; }
    else                      { src = f2; dst = t2; C = 256; P = 196;  tP = 7;  local = bid - nb0 - nb1; }
    int per = tP * (C >> 5);
    int slice = local / per;
    int rem = local - slice * per;
    int cy = rem / tP;
    int cx = rem - cy * tP;
    const float* s = src + (size_t)slice * C * P;
    f16* d = dst + (size_t)slice * C * P;
    int p0 = cx * 32, c0 = cy * 32;
    int tx = threadIdx.x, ty = threadIdx.y;  // 32 x 8
#pragma unroll
    for (int i = 0; i < 32; i += 8) {
        int c = c0 + ty + i, p = p0 + tx;
        if (p < P) tile[ty + i][tx] = s[(size_t)c * P + p];   // c always < C
    }
    __syncthreads();
#pragma unroll
    for (int i = 0; i < 32; i += 8) {
        int p = p0 + ty + i, c = c0 + tx;
        if (p < P) d[(size_t)p * C + c] = (f16)tile[tx][ty + i];
    }
}

struct Corners {
    int p00, p10, p01, p11;
    float w00, w10, w01, w11;
};

__device__ __forceinline__ Corners mk_corners(float gx, float gy, int S) {
    // torch grid_sample: bilinear, zeros padding, align_corners=False
    float x = ((gx + 1.0f) * (float)S - 1.0f) * 0.5f;
    float y = ((gy + 1.0f) * (float)S - 1.0f) * 0.5f;
    float x0f = floorf(x), y0f = floorf(y);
    float wx1 = x - x0f, wy1 = y - y0f;
    float wx0 = 1.0f - wx1, wy0 = 1.0f - wy1;
    int x0 = (int)x0f, y0 = (int)y0f;
    int x1 = x0 + 1, y1 = y0 + 1;
    bool vx0 = (x0 >= 0) && (x0 <= S - 1);
    bool vx1 = (x1 >= 0) && (x1 <= S - 1);
    bool vy0 = (y0 >= 0) && (y0 <= S - 1);
    bool vy1 = (y1 >= 0) && (y1 <= S - 1);
    int xi0 = min(max(x0, 0), S - 1);
    int xi1 = min(max(x1, 0), S - 1);
    int yi0 = min(max(y0, 0), S - 1);
    int yi1 = min(max(y1, 0), S - 1);
    Corners c;
    c.p00 = yi0 * S + xi0;
    c.p10 = yi0 * S + xi1;
    c.p01 = yi1 * S + xi0;
    c.p11 = yi1 * S + xi1;
    c.w00 = wx0 * wy0 * ((vx0 && vy0) ? 1.0f : 0.0f);
    c.w10 = wx1 * wy0 * ((vx1 && vy0) ? 1.0f : 0.0f);
    c.w01 = wx0 * wy1 * ((vx0 && vy1) ? 1.0f : 0.0f);
    c.w11 = wx1 * wy1 * ((vx1 && vy1) ? 1.0f : 0.0f);
    return c;
}

// Per (point, view): compute projection once, emit 3 levels x (4 byte-offsets
// + 4 f32 weights) = 3 x 32B into corn.
__global__ __launch_bounds__(256) void corners_kernel(
    const float* __restrict__ inputs, const float* __restrict__ cams,
    float* __restrict__ corn, int B, int N) {
    int t = blockIdx.x * blockDim.x + threadIdx.x;
    if (t >= B * N * 3) return;
    int point = t / 3;
    int v = t - point * 3;
    int b = point / N;

    const float c_off0 = cams[0], c_off1 = cams[1];
    const float inv_h0 = 1.0f / cams[2], inv_h1 = 1.0f / cams[3];
    const float* cam = cams + 4;

    const float* ip = inputs + (size_t)point * 3;
    const float px = ip[0], py = ip[1], pz = ip[2] - 0.8f;  // + MESH_POS

    const float* m0 = cam + (size_t)(b * 3) * 12;
    const float wx = px * m0[0] + py * m0[3] + pz * m0[6] + m0[9];
    const float wy = px * m0[1] + py * m0[4] + pz * m0[7] + m0[10];
    const float wz = px * m0[2] + py * m0[5] + pz * m0[8] + m0[11];

    const float* m = cam + (size_t)(b * 3 + v) * 12;
    float qx = wx - m[9], qy = wy - m[10], qz = wz - m[11];
    float Xc = m[0] * qx + m[1] * qy + m[2] * qz;
    float Yc = m[3] * qx + m[4] * qy + m[5] * qz;
    float Zc = m[6] * qx + m[7] * qy + m[8] * qz;
    float invZ = 1.0f / Zc;
    float wpix = -248.0f * (Xc * invZ) + c_off0;
    float hpix =  248.0f * (Yc * invZ) + c_off1;
    float gx = fminf(fmaxf(wpix * inv_h0, -1.0f), 1.0f);
    float gy = fminf(fmaxf(hpix * inv_h1, -1.0f), 1.0f);

    float* o = corn + (size_t)t * 24;
    const int S[3] = {56, 28, 14};
    const int CB[3] = {64 * 2, 128 * 2, 256 * 2};  // row bytes factor (f16)
#pragma unroll
    for (int lvl = 0; lvl < 3; ++lvl) {
        Corners cr = mk_corners(gx, gy, S[lvl]);
        o[lvl * 8 + 0] = __int_as_float(cr.p00 * CB[lvl]);
        o[lvl * 8 + 1] = __int_as_float(cr.p10 * CB[lvl]);
        o[lvl * 8 + 2] = __int_as_float(cr.p01 * CB[lvl]);
        o[lvl * 8 + 3] = __int_as_float(cr.p11 * CB[lvl]);
        o[lvl * 8 + 4] = cr.w00;
        o[lvl * 8 + 5] = cr.w10;
        o[lvl * 8 + 6] = cr.w01;
        o[lvl * 8 + 7] = cr.w11;
    }
}

template <int VEC> struct VecOf;
template <> struct VecOf<1> { using T = float; };
template <> struct VecOf<2> { using T = f32x2; };
template <> struct VecOf<4> { using T = f32x4; };
template <int VEC> struct F16VecOf;
template <> struct F16VecOf<1> { using T = f16; };
template <> struct F16VecOf<2> { using T = f16x2; };
template <> struct F16VecOf<4> { using T = f16x4; };

template <int VEC>
__device__ __forceinline__ typename VecOf<VEC>::T
gather4(const f16* __restrict__ base, const int4 off, const float4 w, int lane) {
    using HV = typename F16VecOf<VEC>::T;
    using FV = typename VecOf<VEC>::T;
    const char* cb = (const char*)base;
    const int lo = lane * (VEC * 2);
    HV h00 = *(const HV*)(cb + off.x + lo);
    HV h10 = *(const HV*)(cb + off.y + lo);
    HV h01 = *(const HV*)(cb + off.z + lo);
    HV h11 = *(const HV*)(cb + off.w + lo);
    FV a00, a10, a01, a11;
    if constexpr (VEC == 1) {
        a00 = (float)h00; a10 = (float)h10; a01 = (float)h01; a11 = (float)h11;
    } else {
        a00 = __builtin_convertvector(h00, FV);
        a10 = __builtin_convertvector(h10, FV);
        a01 = __builtin_convertvector(h01, FV);
        a11 = __builtin_convertvector(h11, FV);
    }
    return w.x * a00 + w.y * a10 + w.z * a01 + w.w * a11;
}

template <typename VecT, int VEC>
__device__ __forceinline__ void stats3_nt(VecT a, VecT b, VecT c,
                                          float* pmx, float* pme, float* psd) {
    VecT mx, me, sd;
    const float* pa = (const float*)&a;
    const float* pb = (const float*)&b;
    const float* pc = (const float*)&c;
    float* qx = (float*)&mx; float* qe = (float*)&me; float* qs = (float*)&sd;
#pragma unroll
    for (int j = 0; j < VEC; ++j) {
        float x = pa[j], y = pb[j], z = pc[j];
        float m = fmaxf(x, fmaxf(y, z));
        float mean = (x + y + z) * (1.0f / 3.0f);
        float dx = x - mean, dy = y - mean, dz = z - mean;
        float s = sqrtf((dx * dx + dy * dy + dz * dz) * 0.5f);  // ddof=1
        qx[j] = m; qe[j] = mean; qs[j] = s;
    }
    __builtin_nontemporal_store(mx, (VecT*)pmx);
    __builtin_nontemporal_store(me, (VecT*)pme);
    __builtin_nontemporal_store(sd, (VecT*)psd);
}

// Main kernel, corners precomputed. One point per wave. b = blockIdx.x % B:
// XCD-batch pinning (2.1MB / batch, L2-resident).
__global__ __launch_bounds__(256) void gproj_main_kernel(
    const f16* __restrict__ t0, const f16* __restrict__ t1,
    const f16* __restrict__ t2, const float* __restrict__ inputs,
    const float* __restrict__ corn, float* __restrict__ out, int B, int N) {
    const int wave = threadIdx.x >> 6;
    const int lane = threadIdx.x & 63;
    const int b = blockIdx.x % B;
    const int pib = (blockIdx.x / B) * 4 + wave;
    if (pib >= N) return;
    const int point = b * N + pib;
    const int pu = __builtin_amdgcn_readfirstlane(point);
    const int bu = __builtin_amdgcn_readfirstlane(b);

    const float* ip = inputs + (size_t)point * 3;

    float  v0[3];
    f32x2  v1[3];
    f32x4  v2[3];

#pragma unroll
    for (int v = 0; v < 3; ++v) {
        const float* cp = corn + (size_t)(pu * 3 + v) * 24;
        const int slice = v * B + bu;
        const f16* b0 = t0 + (size_t)slice * 64 * 3136;
        const f16* b1 = t1 + (size_t)slice * 128 * 784;
        const f16* b2 = t2 + (size_t)slice * 256 * 196;

        int4   o0 = *(const int4*)(cp);
        float4 w0 = *(const float4*)(cp + 4);
        int4   o1 = *(const int4*)(cp + 8);
        float4 w1 = *(const float4*)(cp + 12);
        int4   o2 = *(const int4*)(cp + 16);
        float4 w2 = *(const float4*)(cp + 20);

        v0[v] = gather4<1>(b0, o0, w0, lane);   // ch lane
        v1[v] = gather4<2>(b1, o1, w1, lane);   // ch 2*lane..
        v2[v] = gather4<4>(b2, o2, w2, lane);   // ch 4*lane..
    }

    float* op = out + (size_t)point * 1347;
    if (lane < 3) __builtin_nontemporal_store(ip[lane], &op[lane]);

    {   // level0: ch g = lane
        float* basep = op + 3 + lane;
        float mx = fmaxf(v0[0], fmaxf(v0[1], v0[2]));
        float mean = (v0[0] + v0[1] + v0[2]) * (1.0f / 3.0f);
        float dx = v0[0] - mean, dy = v0[1] - mean, dz = v0[2] - mean;
        float sd = sqrtf((dx * dx + dy * dy + dz * dz) * 0.5f);
        __builtin_nontemporal_store(mx, basep);
        __builtin_nontemporal_store(mean, basep + 448);
        __builtin_nontemporal_store(sd, basep + 896);
    }
    {   // level1: ch g = 64 + 2*lane
        const int g = 64 + 2 * lane;
        stats3_nt<f32x2, 2>(v1[0], v1[1], v1[2],
                            op + 3 + g, op + 451 + g, op + 899 + g);
    }
    {   // level2: ch g = 192 + 4*lane
        const int g = 192 + 4 * lane;
        stats3_nt<f32x4, 4>(v2[0], v2[1], v2[2],
                            op + 3 + g, op + 451 + g, op + 899 + g);
    }
}

// ---- mid-fallback: R4 fused kernel (inline corners), f16 feats ----
template <int C, int VEC>
__device__ __forceinline__ typename VecOf<VEC>::T
samph(const f16* __restrict__ base, const Corners& cr, int lane) {
    using HV = typename F16VecOf<VEC>::T;
    using FV = typename VecOf<VEC>::T;
    const HV* r00 = (const HV*)(base + (size_t)cr.p00 * C);
    const HV* r10 = (const HV*)(base + (size_t)cr.p10 * C);
    const HV* r01 = (const HV*)(base + (size_t)cr.p01 * C);
    const HV* r11 = (const HV*)(base + (size_t)cr.p11 * C);
    HV h00 = r00[lane], h10 = r10[lane], h01 = r01[lane], h11 = r11[lane];
    FV a00, a10, a01, a11;
    if constexpr (VEC == 1) {
        a00 = (float)h00; a10 = (float)h10; a01 = (float)h01; a11 = (float)h11;
    } else {
        a00 = __builtin_convertvector(h00, FV);
        a10 = __builtin_convertvector(h10, FV);
        a01 = __builtin_convertvector(h01, FV);
        a11 = __builtin_convertvector(h11, FV);
    }
    return cr.w00 * a00 + cr.w10 * a10 + cr.w01 * a01 + cr.w11 * a11;
}

__global__ __launch_bounds__(256) void gproj_fused_kernel(
    const f16* __restrict__ t0, const f16* __restrict__ t1,
    const f16* __restrict__ t2, const float* __restrict__ inputs,
    const float* __restrict__ cams, float* __restrict__ out, int B, int N) {
    const int wave = threadIdx.x >> 6;
    const int lane = threadIdx.x & 63;
    const int b = blockIdx.x % B;
    const int pib = (blockIdx.x / B) * 4 + wave;
    if (pib >= N) return;
    const int point = b * N + pib;

    const float c_off0 = cams[0], c_off1 = cams[1];
    const float inv_h0 = 1.0f / cams[2], inv_h1 = 1.0f / cams[3];
    const float* cam = cams + 4;

    const float* ip = inputs + (size_t)point * 3;
    const float px = ip[0], py = ip[1], pz = ip[2] - 0.8f;

    const float* m0 = cam + (size_t)(b * 3) * 12;
    const float wx = px * m0[0] + py * m0[3] + pz * m0[6] + m0[9];
    const float wy = px * m0[1] + py * m0[4] + pz * m0[7] + m0[10];
    const float wz = px * m0[2] + py * m0[5] + pz * m0[8] + m0[11];

    float  v0[3];
    f32x2  v1[3];
    f32x4  v2[3];

#pragma unroll
    for (int v = 0; v < 3; ++v) {
        const float* m = cam + (size_t)(b * 3 + v) * 12;
        float qx = wx - m[9], qy = wy - m[10], qz = wz - m[11];
        float Xc = m[0] * qx + m[1] * qy + m[2] * qz;
        float Yc = m[3] * qx + m[4] * qy + m[5] * qz;
        float Zc = m[6] * qx + m[7] * qy + m[8] * qz;
        float invZ = 1.0f / Zc;
        float wpix = -248.0f * (Xc * invZ) + c_off0;
        float hpix =  248.0f * (Yc * invZ) + c_off1;
        float gx = fminf(fmaxf(wpix * inv_h0, -1.0f), 1.0f);
        float gy = fminf(fmaxf(hpix * inv_h1, -1.0f), 1.0f);
        Corners cr0 = mk_corners(gx, gy, 56);
        Corners cr1 = mk_corners(gx, gy, 28);
        Corners cr2 = mk_corners(gx, gy, 14);
        const int slice = v * B + b;
        v0[v] = samph<64, 1>(t0 + (size_t)slice * 64 * 3136, cr0, lane);
        v1[v] = samph<128, 2>(t1 + (size_t)slice * 128 * 784, cr1, lane);
        v2[v] = samph<256, 4>(t2 + (size_t)slice * 256 * 196, cr2, lane);
    }

    float* op = out + (size_t)point * 1347;
    if (lane < 3) __builtin_nontemporal_store(ip[lane], &op[lane]);
    {
        float* basep = op + 3 + lane;
        float mx = fmaxf(v0[0], fmaxf(v0[1], v0[2]));
        float mean = (v0[0] + v0[1] + v0[2]) * (1.0f / 3.0f);
        float dx = v0[0] - mean, dy = v0[1] - mean, dz = v0[2] - mean;
        float sd = sqrtf((dx * dx + dy * dy + dz * dz) * 0.5f);
        __builtin_nontemporal_store(mx, basep);
        __builtin_nontemporal_store(mean, basep + 448);
        __builtin_nontemporal_store(sd, basep + 896);
    }
    {
        const int g = 64 + 2 * lane;
        stats3_nt<f32x2, 2>(v1[0], v1[1], v1[2],
                            op + 3 + g, op + 451 + g, op + 899 + g);
    }
    {
        const int g = 192 + 4 * lane;
        stats3_nt<f32x4, 4>(v2[0], v2[1], v2[2],
                            op + 3 + g, op + 451 + g, op + 899 + g);
    }
}

// ---- last-resort fallback (no workspace): channel-first f32 gathers ----
__device__ __forceinline__ float samp_cf(const float* __restrict__ base,
                                         const Corners& cr, int P, int c) {
    const float* bc = base + (size_t)c * P;
    return cr.w00 * bc[cr.p00] + cr.w10 * bc[cr.p10]
         + cr.w01 * bc[cr.p01] + cr.w11 * bc[cr.p11];
}

__global__ __launch_bounds__(256) void gproj_fallback_kernel(
    const float* __restrict__ f0, const float* __restrict__ f1,
    const float* __restrict__ f2, const float* __restrict__ inputs,
    const float* __restrict__ cams, float* __restrict__ out, int B, int N) {
    const int wave = threadIdx.x >> 6;
    const int lane = threadIdx.x & 63;
    const int point = blockIdx.x * 4 + wave;
    if (point >= B * N) return;
    const int b = point / N;

    const float c_off0 = cams[0], c_off1 = cams[1];
    const float inv_h0 = 1.0f / cams[2], inv_h1 = 1.0f / cams[3];
    const float* cam = cams + 4;

    const float* ip = inputs + (size_t)point * 3;
    const float px = ip[0], py = ip[1], pz = ip[2] - 0.8f;

    const float* m0 = cam + (size_t)(b * 3) * 12;
    const float wx = px * m0[0] + py * m0[3] + pz * m0[6] + m0[9];
    const float wy = px * m0[1] + py * m0[4] + pz * m0[7] + m0[10];
    const float wz = px * m0[2] + py * m0[5] + pz * m0[8] + m0[11];

    float vals[3][7];
#pragma unroll
    for (int v = 0; v < 3; ++v) {
        const float* m = cam + (size_t)(b * 3 + v) * 12;
        float qx = wx - m[9], qy = wy - m[10], qz = wz - m[11];
        float Xc = m[0] * qx + m[1] * qy + m[2] * qz;
        float Yc = m[3] * qx + m[4] * qy + m[5] * qz;
        float Zc = m[6] * qx + m[7] * qy + m[8] * qz;
        float invZ = 1.0f / Zc;
        float wpix = -248.0f * (Xc * invZ) + c_off0;
        float hpix =  248.0f * (Yc * invZ) + c_off1;
        float gx = fminf(fmaxf(wpix * inv_h0, -1.0f), 1.0f);
        float gy = fminf(fmaxf(hpix * inv_h1, -1.0f), 1.0f);
        Corners cr0 = mk_corners(gx, gy, 56);
        Corners cr1 = mk_corners(gx, gy, 28);
        Corners cr2 = mk_corners(gx, gy, 14);
        int slice = v * B + b;
        const float* b0 = f0 + (size_t)slice * 64 * 3136;
        const float* b1 = f1 + (size_t)slice * 128 * 784;
        const float* b2 = f2 + (size_t)slice * 256 * 196;
        vals[v][0] = samp_cf(b0, cr0, 3136, lane);
        vals[v][1] = samp_cf(b1, cr1, 784, lane);
        vals[v][2] = samp_cf(b1, cr1, 784, lane + 64);
        vals[v][3] = samp_cf(b2, cr2, 196, lane);
        vals[v][4] = samp_cf(b2, cr2, 196, lane + 64);
        vals[v][5] = samp_cf(b2, cr2, 196, lane + 128);
        vals[v][6] = samp_cf(b2, cr2, 196, lane + 192);
    }

    float* op = out + (size_t)point * 1347;
    if (lane < 3) op[lane] = ip[lane];
#pragma unroll
    for (int k = 0; k < 7; ++k) {
        float a = vals[0][k], bv = vals[1][k], cv = vals[2][k];
        float mx = fmaxf(a, fmaxf(bv, cv));
        float mean = (a + bv + cv) * (1.0f / 3.0f);
        float da = a - mean, db = bv - mean, dc = cv - mean;
        float sd = sqrtf((da * da + db * db + dc * dc) * 0.5f);
        int g = lane + 64 * k;
        op[3 + g] = mx;
        op[451 + g] = mean;
        op[899 + g] = sd;
    }
}

extern "C" void kernel_launch(void* const* d_in, const int* in_sizes, int n_in,
                              void* d_out, int out_size, void* d_ws, size_t ws_size,
                              hipStream_t stream) {
    const float* feat0 = (const float*)d_in[0];
    const float* feat1 = (const float*)d_in[1];
    const float* feat2 = (const float*)d_in[2];
    const float* inputs = (const float*)d_in[3];
    const float* poses = (const float*)d_in[4];
    const int* resolution = (const int*)d_in[5];
    float* out = (float*)d_out;
    float* ws = (float*)d_ws;

    const int V = 3;
    const int B = in_sizes[4] / (V * 5);
    const int N = in_sizes[3] / (B * 3);
    const int BV = B * V;
    const int total = B * N;

    setup_cams_kernel<<<1, 64, 0, stream>>>(poses, resolution, ws, BV);

    const size_t cams_elems = 512;                     // f32
    const size_t t0_elems = (size_t)BV * 64 * 3136;    // f16
    const size_t t1_elems = (size_t)BV * 128 * 784;
    const size_t t2_elems = (size_t)BV * 256 * 196;
    const size_t th_elems = t0_elems + t1_elems + t2_elems;
    const size_t corn_elems = (size_t)total * 3 * 24;  // f32
    // layout: [cams f32][corn f32][t0/t1/t2 f16]
    const size_t need_mid  = cams_elems * sizeof(float) + th_elems * sizeof(f16);
    const size_t need_full = need_mid + corn_elems * sizeof(float);

    const int nbb = (N + 3) / 4;   // blocks per batch (4 points / 256-thread block)
    const int tgrid = BV * (98 * 2 + 25 * 4 + 7 * 8);
    dim3 tblk(32, 8);

    if (ws_size >= need_full) {
        float* corn = ws + cams_elems;
        f16* t0 = (f16*)(corn + corn_elems);
        f16* t1 = t0 + t0_elems;
        f16* t2 = t1 + t1_elems;
        corners_kernel<<<(total * 3 + 255) / 256, 256, 0, stream>>>(inputs, ws, corn, B, N);
        transpose_all_kernel<<<tgrid, tblk, 0, stream>>>(feat0, feat1, feat2, t0, t1, t2, BV);
        // MEASUREMENT: launch main twice (idempotent — identical writes).
        // M = dur_R6 - dur_R5 isolates the (warm) main-kernel duration.
        gproj_main_kernel<<<B * nbb, 256, 0, stream>>>(t0, t1, t2, inputs, corn, out, B, N);
        gproj_main_kernel<<<B * nbb, 256, 0, stream>>>(t0, t1, t2, inputs, corn, out, B, N);
    } else if (ws_size >= need_mid) {
        f16* t0 = (f16*)(ws + cams_elems);
        f16* t1 = t0 + t0_elems;
        f16* t2 = t1 + t1_elems;
        transpose_all_kernel<<<tgrid, tblk, 0, stream>>>(feat0, feat1, feat2, t0, t1, t2, BV);
        gproj_fused_kernel<<<B * nbb, 256, 0, stream>>>(t0, t1, t2, inputs, ws, out, B, N);
    } else {
        gproj_fallback_kernel<<<(total + 3) / 4, 256, 0, stream>>>(
            feat0, feat1, feat2, inputs, ws, out, B, N);
    }
}

// Round 7
// 109.529 us; speedup vs baseline: 2.1033x; 2.1033x over previous
//
#include <hip/hip_runtime.h>
#include <cstdint>
#include <cmath>

// ---------------------------------------------------------------------------
// GProjection: project B*N points into V=3 views, bilinear-sample 3 feature
// pyramids (64@56x56, 128@28x28, 256@14x14 -> 448 ch), reduce max/mean/std
// over views. Output [B,N,3+3*448] f32.
//
// R7: main kernel writes were 9 misaligned nt segments/point (4B-phase rows,
// 16B stores ≡4 mod 16 -> split lines; nt evict-first risks partial-line RMW).
// Now: stats staged in LDS (stride 1352, +1 shift => all b32/b64/b128 LDS
// writes naturally aligned), then block-cooperative contiguous sweep writes
// the 4-row 21552B region with full-width f32x4/lane stores.
// Corners precompute (R5), f16 channel-last feats (R3), XCD-batch pin (R2).
// ---------------------------------------------------------------------------

typedef float f32x2 __attribute__((ext_vector_type(2)));
typedef float f32x4 __attribute__((ext_vector_type(4)));
typedef _Float16 f16;
typedef _Float16 f16x2 __attribute__((ext_vector_type(2)));
typedef _Float16 f16x4 __attribute__((ext_vector_type(4)));

__global__ void setup_cams_kernel(const float* __restrict__ poses,
                                  const int* __restrict__ resolution,
                                  float* __restrict__ ws, int BV) {
    int t = blockIdx.x * blockDim.x + threadIdx.x;
    if (t == 0) {
        float h0 = ((float)resolution[0] - 1.0f) * 0.5f;
        float h1 = ((float)resolution[1] - 1.0f) * 0.5f;
        ws[0] = 111.5f - h0;   // c_off0
        ws[1] = 111.5f - h1;   // c_off1
        ws[2] = h0;            // half_res0
        ws[3] = h1;            // half_res1
    }
    if (t < BV) {
        const float* p = poses + (size_t)t * 5;
        const float d = 0.017453292519943295f;  // pi/180
        float theta = p[0] * d;
        float elr   = p[1] * d;
        float dist  = p[3];
        float st = sinf(theta), ct = cosf(theta);
        float se = sinf(elr),   ce = cosf(elr);
        float camy = dist * se;
        float lens = dist * ce;
        float camx = lens * ct;
        float camz = lens * st;
        float Zx = camx, Zy = camy, Zz = camz;
        float Yx = -camy * ct, Yy = lens, Yz = -camy * st;  // cos/sin(theta+pi)
        float Xx = Yy * Zz - Yz * Zy;
        float Xy = Yz * Zx - Yx * Zz;
        float Xz = Yx * Zy - Yy * Zx;
        float rx = 1.0f / sqrtf(Xx*Xx + Xy*Xy + Xz*Xz);
        float ry = 1.0f / sqrtf(Yx*Yx + Yy*Yy + Yz*Yz);
        float rz = 1.0f / sqrtf(Zx*Zx + Zy*Zy + Zz*Zz);
        float* c = ws + 4 + (size_t)t * 12;
        c[0] = Xx*rx; c[1] = Xy*rx; c[2] = Xz*rx;
        c[3] = Yx*ry; c[4] = Yy*ry; c[5] = Yz*ry;
        c[6] = Zx*rz; c[7] = Zy*rz; c[8] = Zz*rz;
        c[9] = camx; c[10] = camy; c[11] = camz;
    }
}

// ---- merged transpose: [C][P] f32 -> [P][C] f16, all 3 levels, one grid ----
__global__ void transpose_all_kernel(const float* __restrict__ f0,
                                     const float* __restrict__ f1,
                                     const float* __restrict__ f2,
                                     f16* __restrict__ t0, f16* __restrict__ t1,
                                     f16* __restrict__ t2, int BV) {
    __shared__ float tile[32][33];
    const int nb0 = 98 * 2 * BV;   // P=3136 -> 98 tiles, C=64 -> 2 tiles
    const int nb1 = 25 * 4 * BV;   // P=784  -> 25,      C=128 -> 4
    int bid = blockIdx.x;
    const float* src; f16* dst; int C, P, tP, local;
    if (bid < nb0)            { src = f0; dst = t0; C = 64;  P = 3136; tP = 98; local = bid; }
    else if (bid < nb0 + nb1) { src = f1; dst = t1; C = 128; P = 784;  tP = 25; local = bid - nb0; }
    else                      { src = f2; dst = t2; C = 256; P = 196;  tP = 7;  local = bid - nb0 - nb1; }
    int per = tP * (C >> 5);
    int slice = local / per;
    int rem = local - slice * per;
    int cy = rem / tP;
    int cx = rem - cy * tP;
    const float* s = src + (size_t)slice * C * P;
    f16* d = dst + (size_t)slice * C * P;
    int p0 = cx * 32, c0 = cy * 32;
    int tx = threadIdx.x, ty = threadIdx.y;  // 32 x 8
#pragma unroll
    for (int i = 0; i < 32; i += 8) {
        int c = c0 + ty + i, p = p0 + tx;
        if (p < P) tile[ty + i][tx] = s[(size_t)c * P + p];   // c always < C
    }
    __syncthreads();
#pragma unroll
    for (int i = 0; i < 32; i += 8) {
        int p = p0 + ty + i, c = c0 + tx;
        if (p < P) d[(size_t)p * C + c] = (f16)tile[tx][ty + i];
    }
}

struct Corners {
    int p00, p10, p01, p11;
    float w00, w10, w01, w11;
};

__device__ __forceinline__ Corners mk_corners(float gx, float gy, int S) {
    // torch grid_sample: bilinear, zeros padding, align_corners=False
    float x = ((gx + 1.0f) * (float)S - 1.0f) * 0.5f;
    float y = ((gy + 1.0f) * (float)S - 1.0f) * 0.5f;
    float x0f = floorf(x), y0f = floorf(y);
    float wx1 = x - x0f, wy1 = y - y0f;
    float wx0 = 1.0f - wx1, wy0 = 1.0f - wy1;
    int x0 = (int)x0f, y0 = (int)y0f;
    int x1 = x0 + 1, y1 = y0 + 1;
    bool vx0 = (x0 >= 0) && (x0 <= S - 1);
    bool vx1 = (x1 >= 0) && (x1 <= S - 1);
    bool vy0 = (y0 >= 0) && (y0 <= S - 1);
    bool vy1 = (y1 >= 0) && (y1 <= S - 1);
    int xi0 = min(max(x0, 0), S - 1);
    int xi1 = min(max(x1, 0), S - 1);
    int yi0 = min(max(y0, 0), S - 1);
    int yi1 = min(max(y1, 0), S - 1);
    Corners c;
    c.p00 = yi0 * S + xi0;
    c.p10 = yi0 * S + xi1;
    c.p01 = yi1 * S + xi0;
    c.p11 = yi1 * S + xi1;
    c.w00 = wx0 * wy0 * ((vx0 && vy0) ? 1.0f : 0.0f);
    c.w10 = wx1 * wy0 * ((vx1 && vy0) ? 1.0f : 0.0f);
    c.w01 = wx0 * wy1 * ((vx0 && vy1) ? 1.0f : 0.0f);
    c.w11 = wx1 * wy1 * ((vx1 && vy1) ? 1.0f : 0.0f);
    return c;
}

// Per (point, view): projection once, 3 levels x (4 byte-offsets + 4 weights).
__global__ __launch_bounds__(256) void corners_kernel(
    const float* __restrict__ inputs, const float* __restrict__ cams,
    float* __restrict__ corn, int B, int N) {
    int t = blockIdx.x * blockDim.x + threadIdx.x;
    if (t >= B * N * 3) return;
    int point = t / 3;
    int v = t - point * 3;
    int b = point / N;

    const float c_off0 = cams[0], c_off1 = cams[1];
    const float inv_h0 = 1.0f / cams[2], inv_h1 = 1.0f / cams[3];
    const float* cam = cams + 4;

    const float* ip = inputs + (size_t)point * 3;
    const float px = ip[0], py = ip[1], pz = ip[2] - 0.8f;  // + MESH_POS

    const float* m0 = cam + (size_t)(b * 3) * 12;
    const float wx = px * m0[0] + py * m0[3] + pz * m0[6] + m0[9];
    const float wy = px * m0[1] + py * m0[4] + pz * m0[7] + m0[10];
    const float wz = px * m0[2] + py * m0[5] + pz * m0[8] + m0[11];

    const float* m = cam + (size_t)(b * 3 + v) * 12;
    float qx = wx - m[9], qy = wy - m[10], qz = wz - m[11];
    float Xc = m[0] * qx + m[1] * qy + m[2] * qz;
    float Yc = m[3] * qx + m[4] * qy + m[5] * qz;
    float Zc = m[6] * qx + m[7] * qy + m[8] * qz;
    float invZ = 1.0f / Zc;
    float wpix = -248.0f * (Xc * invZ) + c_off0;
    float hpix =  248.0f * (Yc * invZ) + c_off1;
    float gx = fminf(fmaxf(wpix * inv_h0, -1.0f), 1.0f);
    float gy = fminf(fmaxf(hpix * inv_h1, -1.0f), 1.0f);

    float* o = corn + (size_t)t * 24;
    const int S[3] = {56, 28, 14};
    const int CB[3] = {64 * 2, 128 * 2, 256 * 2};  // row bytes (f16)
#pragma unroll
    for (int lvl = 0; lvl < 3; ++lvl) {
        Corners cr = mk_corners(gx, gy, S[lvl]);
        o[lvl * 8 + 0] = __int_as_float(cr.p00 * CB[lvl]);
        o[lvl * 8 + 1] = __int_as_float(cr.p10 * CB[lvl]);
        o[lvl * 8 + 2] = __int_as_float(cr.p01 * CB[lvl]);
        o[lvl * 8 + 3] = __int_as_float(cr.p11 * CB[lvl]);
        o[lvl * 8 + 4] = cr.w00;
        o[lvl * 8 + 5] = cr.w10;
        o[lvl * 8 + 6] = cr.w01;
        o[lvl * 8 + 7] = cr.w11;
    }
}

template <int VEC> struct VecOf;
template <> struct VecOf<1> { using T = float; };
template <> struct VecOf<2> { using T = f32x2; };
template <> struct VecOf<4> { using T = f32x4; };
template <int VEC> struct F16VecOf;
template <> struct F16VecOf<1> { using T = f16; };
template <> struct F16VecOf<2> { using T = f16x2; };
template <> struct F16VecOf<4> { using T = f16x4; };

template <int VEC>
__device__ __forceinline__ typename VecOf<VEC>::T
gather4(const f16* __restrict__ base, const int4 off, const float4 w, int lane) {
    using HV = typename F16VecOf<VEC>::T;
    using FV = typename VecOf<VEC>::T;
    const char* cb = (const char*)base;
    const int lo = lane * (VEC * 2);
    HV h00 = *(const HV*)(cb + off.x + lo);
    HV h10 = *(const HV*)(cb + off.y + lo);
    HV h01 = *(const HV*)(cb + off.z + lo);
    HV h11 = *(const HV*)(cb + off.w + lo);
    FV a00, a10, a01, a11;
    if constexpr (VEC == 1) {
        a00 = (float)h00; a10 = (float)h10; a01 = (float)h01; a11 = (float)h11;
    } else {
        a00 = __builtin_convertvector(h00, FV);
        a10 = __builtin_convertvector(h10, FV);
        a01 = __builtin_convertvector(h01, FV);
        a11 = __builtin_convertvector(h11, FV);
    }
    return w.x * a00 + w.y * a10 + w.z * a01 + w.w * a11;
}

template <typename VecT, int VEC>
__device__ __forceinline__ void stats3(VecT a, VecT b, VecT c,
                                       VecT* omx, VecT* ome, VecT* osd) {
    const float* pa = (const float*)&a;
    const float* pb = (const float*)&b;
    const float* pc = (const float*)&c;
    float* qx = (float*)omx; float* qe = (float*)ome; float* qs = (float*)osd;
#pragma unroll
    for (int j = 0; j < VEC; ++j) {
        float x = pa[j], y = pb[j], z = pc[j];
        float m = fmaxf(x, fmaxf(y, z));
        float mean = (x + y + z) * (1.0f / 3.0f);
        float dx = x - mean, dy = y - mean, dz = z - mean;
        float s = sqrtf((dx * dx + dy * dy + dz * dz) * 0.5f);  // ddof=1
        qx[j] = m; qe[j] = mean; qs[j] = s;
    }
}

// LDS row stride (floats). +1 shift aligns: level1 (f32x2) at even idx -> 8B,
// level2 (f32x4) at idx%4==0 -> 16B; row base (1352*4=5408 B) is 16B-aligned.
#define ROWS 1352

// Main kernel: 4 points/block (one per wave), stats -> LDS, then contiguous
// block-region sweep. b = blockIdx.x % B: XCD-batch pinning.
__global__ __launch_bounds__(256) void gproj_main_kernel(
    const f16* __restrict__ t0, const f16* __restrict__ t1,
    const f16* __restrict__ t2, const float* __restrict__ inputs,
    const float* __restrict__ corn, float* __restrict__ out, int B, int N) {
    __shared__ float sb[4 * ROWS];
    const int wave = threadIdx.x >> 6;
    const int lane = threadIdx.x & 63;
    const int b = blockIdx.x % B;
    const int pb = (blockIdx.x / B) * 4;   // first point-in-batch of block
    const int pib = pb + wave;
    const bool valid = pib < N;

    if (valid) {
        const int point = b * N + pib;
        const int pu = __builtin_amdgcn_readfirstlane(point);
        const int bu = __builtin_amdgcn_readfirstlane(b);
        const float* ip = inputs + (size_t)point * 3;

        float  v0[3];
        f32x2  v1[3];
        f32x4  v2[3];

#pragma unroll
        for (int v = 0; v < 3; ++v) {
            const float* cp = corn + (size_t)(pu * 3 + v) * 24;
            const int slice = v * B + bu;
            const f16* b0 = t0 + (size_t)slice * 64 * 3136;
            const f16* b1 = t1 + (size_t)slice * 128 * 784;
            const f16* b2 = t2 + (size_t)slice * 256 * 196;

            int4   o0 = *(const int4*)(cp);
            float4 w0 = *(const float4*)(cp + 4);
            int4   o1 = *(const int4*)(cp + 8);
            float4 w1 = *(const float4*)(cp + 12);
            int4   o2 = *(const int4*)(cp + 16);
            float4 w2 = *(const float4*)(cp + 20);

            v0[v] = gather4<1>(b0, o0, w0, lane);
            v1[v] = gather4<2>(b1, o1, w1, lane);
            v2[v] = gather4<4>(b2, o2, w2, lane);
        }

        float* row = sb + wave * ROWS + 1;   // +1 shift for alignment
        if (lane < 3) row[lane] = ip[lane];
        {   // level0: ch lane (scalars)
            float mx = fmaxf(v0[0], fmaxf(v0[1], v0[2]));
            float mean = (v0[0] + v0[1] + v0[2]) * (1.0f / 3.0f);
            float dx = v0[0] - mean, dy = v0[1] - mean, dz = v0[2] - mean;
            float sd = sqrtf((dx * dx + dy * dy + dz * dz) * 0.5f);
            row[3 + lane] = mx;
            row[451 + lane] = mean;
            row[899 + lane] = sd;
        }
        {   // level1: g = 64 + 2*lane -> idx 67+2l (+1 => 68+2l, 8B-aligned)
            f32x2 mx, me, sd;
            stats3<f32x2, 2>(v1[0], v1[1], v1[2], &mx, &me, &sd);
            const int g = 64 + 2 * lane;
            *(f32x2*)(row + 3 + g) = mx;
            *(f32x2*)(row + 451 + g) = me;
            *(f32x2*)(row + 899 + g) = sd;
        }
        {   // level2: g = 192 + 4*lane -> idx 195+4l (+1 => 196+4l, 16B)
            f32x4 mx, me, sd;
            stats3<f32x4, 4>(v2[0], v2[1], v2[2], &mx, &me, &sd);
            const int g = 192 + 4 * lane;
            *(f32x4*)(row + 3 + g) = mx;
            *(f32x4*)(row + 451 + g) = me;
            *(f32x4*)(row + 899 + g) = sd;
        }
    }
    __syncthreads();

    // cooperative contiguous sweep of the block's rows
    const int nvalid = min(N - pb, 4);
    const int len = nvalid * 1347;           // floats in region
    float* gout = out + (size_t)(b * N + pb) * 1347;
    const int nch = len >> 2;                // float4 chunks
    for (int c = threadIdx.x; c < nch; c += 256) {
        const int j = c * 4;
        f32x4 vv;
#pragma unroll
        for (int e = 0; e < 4; ++e) {
            const int jj = j + e;
            const int r = (jj >= 2694) ? ((jj >= 4041) ? 3 : 2)
                                       : ((jj >= 1347) ? 1 : 0);
            vv[e] = sb[r * ROWS + 1 + (jj - r * 1347)];
        }
        __builtin_nontemporal_store(vv, (f32x4*)(gout + j));
    }
    if ((len & 3) && threadIdx.x == 0) {     // tail only if nvalid < 4
        for (int jj = nch * 4; jj < len; ++jj) {
            const int r = (jj >= 2694) ? ((jj >= 4041) ? 3 : 2)
                                       : ((jj >= 1347) ? 1 : 0);
            gout[jj] = sb[r * ROWS + 1 + (jj - r * 1347)];
        }
    }
}

// ---- mid-fallback: fused kernel (inline corners), f16 feats, direct stores --
template <int C, int VEC>
__device__ __forceinline__ typename VecOf<VEC>::T
samph(const f16* __restrict__ base, const Corners& cr, int lane) {
    using HV = typename F16VecOf<VEC>::T;
    using FV = typename VecOf<VEC>::T;
    const HV* r00 = (const HV*)(base + (size_t)cr.p00 * C);
    const HV* r10 = (const HV*)(base + (size_t)cr.p10 * C);
    const HV* r01 = (const HV*)(base + (size_t)cr.p01 * C);
    const HV* r11 = (const HV*)(base + (size_t)cr.p11 * C);
    HV h00 = r00[lane], h10 = r10[lane], h01 = r01[lane], h11 = r11[lane];
    FV a00, a10, a01, a11;
    if constexpr (VEC == 1) {
        a00 = (float)h00; a10 = (float)h10; a01 = (float)h01; a11 = (float)h11;
    } else {
        a00 = __builtin_convertvector(h00, FV);
        a10 = __builtin_convertvector(h10, FV);
        a01 = __builtin_convertvector(h01, FV);
        a11 = __builtin_convertvector(h11, FV);
    }
    return cr.w00 * a00 + cr.w10 * a10 + cr.w01 * a01 + cr.w11 * a11;
}

template <typename VecT, int VEC>
__device__ __forceinline__ void stats3_st(VecT a, VecT b, VecT c,
                                          float* pmx, float* pme, float* psd) {
    VecT mx, me, sd;
    stats3<VecT, VEC>(a, b, c, &mx, &me, &sd);
    *(VecT*)pmx = mx; *(VecT*)pme = me; *(VecT*)psd = sd;
}

__global__ __launch_bounds__(256) void gproj_fused_kernel(
    const f16* __restrict__ t0, const f16* __restrict__ t1,
    const f16* __restrict__ t2, const float* __restrict__ inputs,
    const float* __restrict__ cams, float* __restrict__ out, int B, int N) {
    const int wave = threadIdx.x >> 6;
    const int lane = threadIdx.x & 63;
    const int b = blockIdx.x % B;
    const int pib = (blockIdx.x / B) * 4 + wave;
    if (pib >= N) return;
    const int point = b * N + pib;

    const float c_off0 = cams[0], c_off1 = cams[1];
    const float inv_h0 = 1.0f / cams[2], inv_h1 = 1.0f / cams[3];
    const float* cam = cams + 4;

    const float* ip = inputs + (size_t)point * 3;
    const float px = ip[0], py = ip[1], pz = ip[2] - 0.8f;

    const float* m0 = cam + (size_t)(b * 3) * 12;
    const float wx = px * m0[0] + py * m0[3] + pz * m0[6] + m0[9];
    const float wy = px * m0[1] + py * m0[4] + pz * m0[7] + m0[10];
    const float wz = px * m0[2] + py * m0[5] + pz * m0[8] + m0[11];

    float  v0[3];
    f32x2  v1[3];
    f32x4  v2[3];

#pragma unroll
    for (int v = 0; v < 3; ++v) {
        const float* m = cam + (size_t)(b * 3 + v) * 12;
        float qx = wx - m[9], qy = wy - m[10], qz = wz - m[11];
        float Xc = m[0] * qx + m[1] * qy + m[2] * qz;
        float Yc = m[3] * qx + m[4] * qy + m[5] * qz;
        float Zc = m[6] * qx + m[7] * qy + m[8] * qz;
        float invZ = 1.0f / Zc;
        float wpix = -248.0f * (Xc * invZ) + c_off0;
        float hpix =  248.0f * (Yc * invZ) + c_off1;
        float gx = fminf(fmaxf(wpix * inv_h0, -1.0f), 1.0f);
        float gy = fminf(fmaxf(hpix * inv_h1, -1.0f), 1.0f);
        Corners cr0 = mk_corners(gx, gy, 56);
        Corners cr1 = mk_corners(gx, gy, 28);
        Corners cr2 = mk_corners(gx, gy, 14);
        const int slice = v * B + b;
        v0[v] = samph<64, 1>(t0 + (size_t)slice * 64 * 3136, cr0, lane);
        v1[v] = samph<128, 2>(t1 + (size_t)slice * 128 * 784, cr1, lane);
        v2[v] = samph<256, 4>(t2 + (size_t)slice * 256 * 196, cr2, lane);
    }

    float* op = out + (size_t)point * 1347;
    if (lane < 3) op[lane] = ip[lane];
    {
        float* basep = op + 3 + lane;
        float mx = fmaxf(v0[0], fmaxf(v0[1], v0[2]));
        float mean = (v0[0] + v0[1] + v0[2]) * (1.0f / 3.0f);
        float dx = v0[0] - mean, dy = v0[1] - mean, dz = v0[2] - mean;
        float sd = sqrtf((dx * dx + dy * dy + dz * dz) * 0.5f);
        basep[0] = mx; basep[448] = mean; basep[896] = sd;
    }
    {
        const int g = 64 + 2 * lane;
        stats3_st<f32x2, 2>(v1[0], v1[1], v1[2],
                            op + 3 + g, op + 451 + g, op + 899 + g);
    }
    {
        const int g = 192 + 4 * lane;
        stats3_st<f32x4, 4>(v2[0], v2[1], v2[2],
                            op + 3 + g, op + 451 + g, op + 899 + g);
    }
}

// ---- last-resort fallback (no workspace): channel-first f32 gathers ----
__device__ __forceinline__ float samp_cf(const float* __restrict__ base,
                                         const Corners& cr, int P, int c) {
    const float* bc = base + (size_t)c * P;
    return cr.w00 * bc[cr.p00] + cr.w10 * bc[cr.p10]
         + cr.w01 * bc[cr.p01] + cr.w11 * bc[cr.p11];
}

__global__ __launch_bounds__(256) void gproj_fallback_kernel(
    const float* __restrict__ f0, const float* __restrict__ f1,
    const float* __restrict__ f2, const float* __restrict__ inputs,
    const float* __restrict__ cams, float* __restrict__ out, int B, int N) {
    const int wave = threadIdx.x >> 6;
    const int lane = threadIdx.x & 63;
    const int point = blockIdx.x * 4 + wave;
    if (point >= B * N) return;
    const int b = point / N;

    const float c_off0 = cams[0], c_off1 = cams[1];
    const float inv_h0 = 1.0f / cams[2], inv_h1 = 1.0f / cams[3];
    const float* cam = cams + 4;

    const float* ip = inputs + (size_t)point * 3;
    const float px = ip[0], py = ip[1], pz = ip[2] - 0.8f;

    const float* m0 = cam + (size_t)(b * 3) * 12;
    const float wx = px * m0[0] + py * m0[3] + pz * m0[6] + m0[9];
    const float wy = px * m0[1] + py * m0[4] + pz * m0[7] + m0[10];
    const float wz = px * m0[2] + py * m0[5] + pz * m0[8] + m0[11];

    float vals[3][7];
#pragma unroll
    for (int v = 0; v < 3; ++v) {
        const float* m = cam + (size_t)(b * 3 + v) * 12;
        float qx = wx - m[9], qy = wy - m[10], qz = wz - m[11];
        float Xc = m[0] * qx + m[1] * qy + m[2] * qz;
        float Yc = m[3] * qx + m[4] * qy + m[5] * qz;
        float Zc = m[6] * qx + m[7] * qy + m[8] * qz;
        float invZ = 1.0f / Zc;
        float wpix = -248.0f * (Xc * invZ) + c_off0;
        float hpix =  248.0f * (Yc * invZ) + c_off1;
        float gx = fminf(fmaxf(wpix * inv_h0, -1.0f), 1.0f);
        float gy = fminf(fmaxf(hpix * inv_h1, -1.0f), 1.0f);
        Corners cr0 = mk_corners(gx, gy, 56);
        Corners cr1 = mk_corners(gx, gy, 28);
        Corners cr2 = mk_corners(gx, gy, 14);
        int slice = v * B + b;
        const float* b0 = f0 + (size_t)slice * 64 * 3136;
        const float* b1 = f1 + (size_t)slice * 128 * 784;
        const float* b2 = f2 + (size_t)slice * 256 * 196;
        vals[v][0] = samp_cf(b0, cr0, 3136, lane);
        vals[v][1] = samp_cf(b1, cr1, 784, lane);
        vals[v][2] = samp_cf(b1, cr1, 784, lane + 64);
        vals[v][3] = samp_cf(b2, cr2, 196, lane);
        vals[v][4] = samp_cf(b2, cr2, 196, lane + 64);
        vals[v][5] = samp_cf(b2, cr2, 196, lane + 128);
        vals[v][6] = samp_cf(b2, cr2, 196, lane + 192);
    }

    float* op = out + (size_t)point * 1347;
    if (lane < 3) op[lane] = ip[lane];
#pragma unroll
    for (int k = 0; k < 7; ++k) {
        float a = vals[0][k], bv = vals[1][k], cv = vals[2][k];
        float mx = fmaxf(a, fmaxf(bv, cv));
        float mean = (a + bv + cv) * (1.0f / 3.0f);
        float da = a - mean, db = bv - mean, dc = cv - mean;
        float sd = sqrtf((da * da + db * db + dc * dc) * 0.5f);
        int g = lane + 64 * k;
        op[3 + g] = mx;
        op[451 + g] = mean;
        op[899 + g] = sd;
    }
}

extern "C" void kernel_launch(void* const* d_in, const int* in_sizes, int n_in,
                              void* d_out, int out_size, void* d_ws, size_t ws_size,
                              hipStream_t stream) {
    const float* feat0 = (const float*)d_in[0];
    const float* feat1 = (const float*)d_in[1];
    const float* feat2 = (const float*)d_in[2];
    const float* inputs = (const float*)d_in[3];
    const float* poses = (const float*)d_in[4];
    const int* resolution = (const int*)d_in[5];
    float* out = (float*)d_out;
    float* ws = (float*)d_ws;

    const int V = 3;
    const int B = in_sizes[4] / (V * 5);
    const int N = in_sizes[3] / (B * 3);
    const int BV = B * V;
    const int total = B * N;

    setup_cams_kernel<<<1, 64, 0, stream>>>(poses, resolution, ws, BV);

    const size_t cams_elems = 512;                     // f32
    const size_t t0_elems = (size_t)BV * 64 * 3136;    // f16
    const size_t t1_elems = (size_t)BV * 128 * 784;
    const size_t t2_elems = (size_t)BV * 256 * 196;
    const size_t th_elems = t0_elems + t1_elems + t2_elems;
    const size_t corn_elems = (size_t)total * 3 * 24;  // f32
    const size_t need_mid  = cams_elems * sizeof(float) + th_elems * sizeof(f16);
    const size_t need_full = need_mid + corn_elems * sizeof(float);

    const int nbb = (N + 3) / 4;   // blocks per batch
    const int tgrid = BV * (98 * 2 + 25 * 4 + 7 * 8);
    dim3 tblk(32, 8);

    if (ws_size >= need_full) {
        float* corn = ws + cams_elems;
        f16* t0 = (f16*)(corn + corn_elems);
        f16* t1 = t0 + t0_elems;
        f16* t2 = t1 + t1_elems;
        corners_kernel<<<(total * 3 + 255) / 256, 256, 0, stream>>>(inputs, ws, corn, B, N);
        transpose_all_kernel<<<tgrid, tblk, 0, stream>>>(feat0, feat1, feat2, t0, t1, t2, BV);
        gproj_main_kernel<<<B * nbb, 256, 0, stream>>>(t0, t1, t2, inputs, corn, out, B, N);
    } else if (ws_size >= need_mid) {
        f16* t0 = (f16*)(ws + cams_elems);
        f16* t1 = t0 + t0_elems;
        f16* t2 = t1 + t1_elems;
        transpose_all_kernel<<<tgrid, tblk, 0, stream>>>(feat0, feat1, feat2, t0, t1, t2, BV);
        gproj_fused_kernel<<<B * nbb, 256, 0, stream>>>(t0, t1, t2, inputs, ws, out, B, N);
    } else {
        gproj_fallback_kernel<<<(total + 3) / 4, 256, 0, stream>>>(
            feat0, feat1, feat2, inputs, ws, out, B, N);
    }
}

// Round 8
// 101.366 us; speedup vs baseline: 2.2728x; 1.0805x over previous
//
#include <hip/hip_runtime.h>
#include <cstdint>
#include <cmath>

// ---------------------------------------------------------------------------
// GProjection: project B*N points into V=3 views, bilinear-sample 3 feature
// pyramids (64@56x56, 128@28x28, 256@14x14 -> 448 ch), reduce max/mean/std
// over views. Output [B,N,3+3*448] f32.
//
// R8: full path collapsed to TWO launches.
//  prep_kernel = transpose tiles (f32 [C][P] -> f16 [P][C]) UNION corner
//  blocks (projection per (point,view), cams computed inline per-thread —
//  no cross-kernel dependency, no cross-block ordering assumed).
//  main kernel (unchanged from R7): scalar-hoisted corner loads, f16
//  channel-last vec gathers, XCD-batch pinning, LDS-staged stats, aligned
//  contiguous nt block-region sweep.
// ---------------------------------------------------------------------------

typedef float f32x2 __attribute__((ext_vector_type(2)));
typedef float f32x4 __attribute__((ext_vector_type(4)));
typedef _Float16 f16;
typedef _Float16 f16x2 __attribute__((ext_vector_type(2)));
typedef _Float16 f16x4 __attribute__((ext_vector_type(4)));

// ---- camera matrix from a pose row (shared by setup + inline corners) ----
__device__ __forceinline__ void make_cam(const float* __restrict__ p, float* c) {
    const float d = 0.017453292519943295f;  // pi/180
    float theta = p[0] * d;
    float elr   = p[1] * d;
    float dist  = p[3];
    float st = sinf(theta), ct = cosf(theta);
    float se = sinf(elr),   ce = cosf(elr);
    float camy = dist * se;
    float lens = dist * ce;
    float camx = lens * ct;
    float camz = lens * st;
    float Zx = camx, Zy = camy, Zz = camz;
    float Yx = -camy * ct, Yy = lens, Yz = -camy * st;  // cos/sin(theta+pi)
    float Xx = Yy * Zz - Yz * Zy;
    float Xy = Yz * Zx - Yx * Zz;
    float Xz = Yx * Zy - Yy * Zx;
    float rx = 1.0f / sqrtf(Xx*Xx + Xy*Xy + Xz*Xz);
    float ry = 1.0f / sqrtf(Yx*Yx + Yy*Yy + Yz*Yz);
    float rz = 1.0f / sqrtf(Zx*Zx + Zy*Zy + Zz*Zz);
    c[0] = Xx*rx; c[1] = Xy*rx; c[2] = Xz*rx;
    c[3] = Yx*ry; c[4] = Yy*ry; c[5] = Yz*ry;
    c[6] = Zx*rz; c[7] = Zy*rz; c[8] = Zz*rz;
    c[9] = camx; c[10] = camy; c[11] = camz;
}

__global__ void setup_cams_kernel(const float* __restrict__ poses,
                                  const int* __restrict__ resolution,
                                  float* __restrict__ ws, int BV) {
    int t = blockIdx.x * blockDim.x + threadIdx.x;
    if (t == 0) {
        float h0 = ((float)resolution[0] - 1.0f) * 0.5f;
        float h1 = ((float)resolution[1] - 1.0f) * 0.5f;
        ws[0] = 111.5f - h0;   // c_off0
        ws[1] = 111.5f - h1;   // c_off1
        ws[2] = h0;            // half_res0
        ws[3] = h1;            // half_res1
    }
    if (t < BV) make_cam(poses + (size_t)t * 5, ws + 4 + (size_t)t * 12);
}

struct Corners {
    int p00, p10, p01, p11;
    float w00, w10, w01, w11;
};

__device__ __forceinline__ Corners mk_corners(float gx, float gy, int S) {
    // torch grid_sample: bilinear, zeros padding, align_corners=False
    float x = ((gx + 1.0f) * (float)S - 1.0f) * 0.5f;
    float y = ((gy + 1.0f) * (float)S - 1.0f) * 0.5f;
    float x0f = floorf(x), y0f = floorf(y);
    float wx1 = x - x0f, wy1 = y - y0f;
    float wx0 = 1.0f - wx1, wy0 = 1.0f - wy1;
    int x0 = (int)x0f, y0 = (int)y0f;
    int x1 = x0 + 1, y1 = y0 + 1;
    bool vx0 = (x0 >= 0) && (x0 <= S - 1);
    bool vx1 = (x1 >= 0) && (x1 <= S - 1);
    bool vy0 = (y0 >= 0) && (y0 <= S - 1);
    bool vy1 = (y1 >= 0) && (y1 <= S - 1);
    int xi0 = min(max(x0, 0), S - 1);
    int xi1 = min(max(x1, 0), S - 1);
    int yi0 = min(max(y0, 0), S - 1);
    int yi1 = min(max(y1, 0), S - 1);
    Corners c;
    c.p00 = yi0 * S + xi0;
    c.p10 = yi0 * S + xi1;
    c.p01 = yi1 * S + xi0;
    c.p11 = yi1 * S + xi1;
    c.w00 = wx0 * wy0 * ((vx0 && vy0) ? 1.0f : 0.0f);
    c.w10 = wx1 * wy0 * ((vx1 && vy0) ? 1.0f : 0.0f);
    c.w01 = wx0 * wy1 * ((vx0 && vy1) ? 1.0f : 0.0f);
    c.w11 = wx1 * wy1 * ((vx1 && vy1) ? 1.0f : 0.0f);
    return c;
}

// ---- prep kernel: transpose tiles UNION corner blocks, one dispatch ----
// blocks [0, tgrid): transpose; blocks [tgrid, tgrid+cgrid): corners.
__global__ __launch_bounds__(256) void prep_kernel(
    const float* __restrict__ f0, const float* __restrict__ f1,
    const float* __restrict__ f2, f16* __restrict__ t0, f16* __restrict__ t1,
    f16* __restrict__ t2, const float* __restrict__ inputs,
    const float* __restrict__ poses, const int* __restrict__ resolution,
    float* __restrict__ corn, int B, int N, int BV, int tgrid) {
    __shared__ float tile[32][33];
    const int bid = blockIdx.x;
    if (bid < tgrid) {
        // ---------------- transpose part ----------------
        const int nb0 = 98 * 2 * BV;   // P=3136: 98 p-tiles x 2 c-tiles
        const int nb1 = 25 * 4 * BV;   // P=784 : 25 x 4
        const float* src; f16* dst; int C, P, tP, local;
        if (bid < nb0)            { src = f0; dst = t0; C = 64;  P = 3136; tP = 98; local = bid; }
        else if (bid < nb0 + nb1) { src = f1; dst = t1; C = 128; P = 784;  tP = 25; local = bid - nb0; }
        else                      { src = f2; dst = t2; C = 256; P = 196;  tP = 7;  local = bid - nb0 - nb1; }
        int per = tP * (C >> 5);
        int slice = local / per;
        int rem = local - slice * per;
        int cy = rem / tP;
        int cx = rem - cy * tP;
        const float* s = src + (size_t)slice * C * P;
        f16* d = dst + (size_t)slice * C * P;
        int p0 = cx * 32, c0 = cy * 32;
        int tx = threadIdx.x & 31, ty = threadIdx.x >> 5;  // 32 x 8
#pragma unroll
        for (int i = 0; i < 32; i += 8) {
            int c = c0 + ty + i, p = p0 + tx;
            if (p < P) tile[ty + i][tx] = s[(size_t)c * P + p];
        }
        __syncthreads();
#pragma unroll
        for (int i = 0; i < 32; i += 8) {
            int p = p0 + ty + i, c = c0 + tx;
            if (p < P) d[(size_t)p * C + c] = (f16)tile[tx][ty + i];
        }
    } else {
        // ---------------- corners part (cams inline) ----------------
        int t = (bid - tgrid) * 256 + threadIdx.x;
        if (t >= B * N * 3) return;
        int point = t / 3;
        int v = t - point * 3;
        int b = point / N;

        float h0 = ((float)resolution[0] - 1.0f) * 0.5f;
        float h1 = ((float)resolution[1] - 1.0f) * 0.5f;
        float c_off0 = 111.5f - h0, c_off1 = 111.5f - h1;
        float inv_h0 = 1.0f / h0, inv_h1 = 1.0f / h1;

        float cm0[12], cmv[12];
        make_cam(poses + (size_t)(b * 3) * 5, cm0);
        make_cam(poses + (size_t)(b * 3 + v) * 5, cmv);

        const float* ip = inputs + (size_t)point * 3;
        const float px = ip[0], py = ip[1], pz = ip[2] - 0.8f;  // + MESH_POS

        const float wx = px * cm0[0] + py * cm0[3] + pz * cm0[6] + cm0[9];
        const float wy = px * cm0[1] + py * cm0[4] + pz * cm0[7] + cm0[10];
        const float wz = px * cm0[2] + py * cm0[5] + pz * cm0[8] + cm0[11];

        float qx = wx - cmv[9], qy = wy - cmv[10], qz = wz - cmv[11];
        float Xc = cmv[0] * qx + cmv[1] * qy + cmv[2] * qz;
        float Yc = cmv[3] * qx + cmv[4] * qy + cmv[5] * qz;
        float Zc = cmv[6] * qx + cmv[7] * qy + cmv[8] * qz;
        float invZ = 1.0f / Zc;
        float wpix = -248.0f * (Xc * invZ) + c_off0;
        float hpix =  248.0f * (Yc * invZ) + c_off1;
        float gx = fminf(fmaxf(wpix * inv_h0, -1.0f), 1.0f);
        float gy = fminf(fmaxf(hpix * inv_h1, -1.0f), 1.0f);

        float* o = corn + (size_t)t * 24;
        const int S[3] = {56, 28, 14};
        const int CB[3] = {64 * 2, 128 * 2, 256 * 2};  // row bytes (f16)
#pragma unroll
        for (int lvl = 0; lvl < 3; ++lvl) {
            Corners cr = mk_corners(gx, gy, S[lvl]);
            o[lvl * 8 + 0] = __int_as_float(cr.p00 * CB[lvl]);
            o[lvl * 8 + 1] = __int_as_float(cr.p10 * CB[lvl]);
            o[lvl * 8 + 2] = __int_as_float(cr.p01 * CB[lvl]);
            o[lvl * 8 + 3] = __int_as_float(cr.p11 * CB[lvl]);
            o[lvl * 8 + 4] = cr.w00;
            o[lvl * 8 + 5] = cr.w10;
            o[lvl * 8 + 6] = cr.w01;
            o[lvl * 8 + 7] = cr.w11;
        }
    }
}

template <int VEC> struct VecOf;
template <> struct VecOf<1> { using T = float; };
template <> struct VecOf<2> { using T = f32x2; };
template <> struct VecOf<4> { using T = f32x4; };
template <int VEC> struct F16VecOf;
template <> struct F16VecOf<1> { using T = f16; };
template <> struct F16VecOf<2> { using T = f16x2; };
template <> struct F16VecOf<4> { using T = f16x4; };

template <int VEC>
__device__ __forceinline__ typename VecOf<VEC>::T
gather4(const f16* __restrict__ base, const int4 off, const float4 w, int lane) {
    using HV = typename F16VecOf<VEC>::T;
    using FV = typename VecOf<VEC>::T;
    const char* cb = (const char*)base;
    const int lo = lane * (VEC * 2);
    HV h00 = *(const HV*)(cb + off.x + lo);
    HV h10 = *(const HV*)(cb + off.y + lo);
    HV h01 = *(const HV*)(cb + off.z + lo);
    HV h11 = *(const HV*)(cb + off.w + lo);
    FV a00, a10, a01, a11;
    if constexpr (VEC == 1) {
        a00 = (float)h00; a10 = (float)h10; a01 = (float)h01; a11 = (float)h11;
    } else {
        a00 = __builtin_convertvector(h00, FV);
        a10 = __builtin_convertvector(h10, FV);
        a01 = __builtin_convertvector(h01, FV);
        a11 = __builtin_convertvector(h11, FV);
    }
    return w.x * a00 + w.y * a10 + w.z * a01 + w.w * a11;
}

template <typename VecT, int VEC>
__device__ __forceinline__ void stats3(VecT a, VecT b, VecT c,
                                       VecT* omx, VecT* ome, VecT* osd) {
    const float* pa = (const float*)&a;
    const float* pb = (const float*)&b;
    const float* pc = (const float*)&c;
    float* qx = (float*)omx; float* qe = (float*)ome; float* qs = (float*)osd;
#pragma unroll
    for (int j = 0; j < VEC; ++j) {
        float x = pa[j], y = pb[j], z = pc[j];
        float m = fmaxf(x, fmaxf(y, z));
        float mean = (x + y + z) * (1.0f / 3.0f);
        float dx = x - mean, dy = y - mean, dz = z - mean;
        float s = sqrtf((dx * dx + dy * dy + dz * dz) * 0.5f);  // ddof=1
        qx[j] = m; qe[j] = mean; qs[j] = s;
    }
}

// LDS row stride (floats). +1 shift aligns level1 (8B) / level2 (16B) writes.
#define ROWS 1352

// Main kernel (unchanged from R7): 4 points/block, stats -> LDS, contiguous
// aligned nt sweep. b = blockIdx.x % B: XCD-batch pinning.
__global__ __launch_bounds__(256) void gproj_main_kernel(
    const f16* __restrict__ t0, const f16* __restrict__ t1,
    const f16* __restrict__ t2, const float* __restrict__ inputs,
    const float* __restrict__ corn, float* __restrict__ out, int B, int N) {
    __shared__ float sb[4 * ROWS];
    const int wave = threadIdx.x >> 6;
    const int lane = threadIdx.x & 63;
    const int b = blockIdx.x % B;
    const int pb = (blockIdx.x / B) * 4;
    const int pib = pb + wave;
    const bool valid = pib < N;

    if (valid) {
        const int point = b * N + pib;
        const int pu = __builtin_amdgcn_readfirstlane(point);
        const int bu = __builtin_amdgcn_readfirstlane(b);
        const float* ip = inputs + (size_t)point * 3;

        float  v0[3];
        f32x2  v1[3];
        f32x4  v2[3];

#pragma unroll
        for (int v = 0; v < 3; ++v) {
            const float* cp = corn + (size_t)(pu * 3 + v) * 24;
            const int slice = v * B + bu;
            const f16* b0 = t0 + (size_t)slice * 64 * 3136;
            const f16* b1 = t1 + (size_t)slice * 128 * 784;
            const f16* b2 = t2 + (size_t)slice * 256 * 196;

            int4   o0 = *(const int4*)(cp);
            float4 w0 = *(const float4*)(cp + 4);
            int4   o1 = *(const int4*)(cp + 8);
            float4 w1 = *(const float4*)(cp + 12);
            int4   o2 = *(const int4*)(cp + 16);
            float4 w2 = *(const float4*)(cp + 20);

            v0[v] = gather4<1>(b0, o0, w0, lane);
            v1[v] = gather4<2>(b1, o1, w1, lane);
            v2[v] = gather4<4>(b2, o2, w2, lane);
        }

        float* row = sb + wave * ROWS + 1;
        if (lane < 3) row[lane] = ip[lane];
        {   // level0
            float mx = fmaxf(v0[0], fmaxf(v0[1], v0[2]));
            float mean = (v0[0] + v0[1] + v0[2]) * (1.0f / 3.0f);
            float dx = v0[0] - mean, dy = v0[1] - mean, dz = v0[2] - mean;
            float sd = sqrtf((dx * dx + dy * dy + dz * dz) * 0.5f);
            row[3 + lane] = mx;
            row[451 + lane] = mean;
            row[899 + lane] = sd;
        }
        {   // level1
            f32x2 mx, me, sd;
            stats3<f32x2, 2>(v1[0], v1[1], v1[2], &mx, &me, &sd);
            const int g = 64 + 2 * lane;
            *(f32x2*)(row + 3 + g) = mx;
            *(f32x2*)(row + 451 + g) = me;
            *(f32x2*)(row + 899 + g) = sd;
        }
        {   // level2
            f32x4 mx, me, sd;
            stats3<f32x4, 4>(v2[0], v2[1], v2[2], &mx, &me, &sd);
            const int g = 192 + 4 * lane;
            *(f32x4*)(row + 3 + g) = mx;
            *(f32x4*)(row + 451 + g) = me;
            *(f32x4*)(row + 899 + g) = sd;
        }
    }
    __syncthreads();

    const int nvalid = min(N - pb, 4);
    const int len = nvalid * 1347;
    float* gout = out + (size_t)(b * N + pb) * 1347;
    const int nch = len >> 2;
    for (int c = threadIdx.x; c < nch; c += 256) {
        const int j = c * 4;
        f32x4 vv;
#pragma unroll
        for (int e = 0; e < 4; ++e) {
            const int jj = j + e;
            const int r = (jj >= 2694) ? ((jj >= 4041) ? 3 : 2)
                                       : ((jj >= 1347) ? 1 : 0);
            vv[e] = sb[r * ROWS + 1 + (jj - r * 1347)];
        }
        __builtin_nontemporal_store(vv, (f32x4*)(gout + j));
    }
    if ((len & 3) && threadIdx.x == 0) {
        for (int jj = nch * 4; jj < len; ++jj) {
            const int r = (jj >= 2694) ? ((jj >= 4041) ? 3 : 2)
                                       : ((jj >= 1347) ? 1 : 0);
            gout[jj] = sb[r * ROWS + 1 + (jj - r * 1347)];
        }
    }
}

// ---- mid-fallback: fused kernel (inline corners), f16 feats ----
template <int C, int VEC>
__device__ __forceinline__ typename VecOf<VEC>::T
samph(const f16* __restrict__ base, const Corners& cr, int lane) {
    using HV = typename F16VecOf<VEC>::T;
    using FV = typename VecOf<VEC>::T;
    const HV* r00 = (const HV*)(base + (size_t)cr.p00 * C);
    const HV* r10 = (const HV*)(base + (size_t)cr.p10 * C);
    const HV* r01 = (const HV*)(base + (size_t)cr.p01 * C);
    const HV* r11 = (const HV*)(base + (size_t)cr.p11 * C);
    HV h00 = r00[lane], h10 = r10[lane], h01 = r01[lane], h11 = r11[lane];
    FV a00, a10, a01, a11;
    if constexpr (VEC == 1) {
        a00 = (float)h00; a10 = (float)h10; a01 = (float)h01; a11 = (float)h11;
    } else {
        a00 = __builtin_convertvector(h00, FV);
        a10 = __builtin_convertvector(h10, FV);
        a01 = __builtin_convertvector(h01, FV);
        a11 = __builtin_convertvector(h11, FV);
    }
    return cr.w00 * a00 + cr.w10 * a10 + cr.w01 * a01 + cr.w11 * a11;
}

template <typename VecT, int VEC>
__device__ __forceinline__ void stats3_st(VecT a, VecT b, VecT c,
                                          float* pmx, float* pme, float* psd) {
    VecT mx, me, sd;
    stats3<VecT, VEC>(a, b, c, &mx, &me, &sd);
    *(VecT*)pmx = mx; *(VecT*)pme = me; *(VecT*)psd = sd;
}

__global__ __launch_bounds__(256) void gproj_fused_kernel(
    const f16* __restrict__ t0, const f16* __restrict__ t1,
    const f16* __restrict__ t2, const float* __restrict__ inputs,
    const float* __restrict__ cams, float* __restrict__ out, int B, int N) {
    const int wave = threadIdx.x >> 6;
    const int lane = threadIdx.x & 63;
    const int b = blockIdx.x % B;
    const int pib = (blockIdx.x / B) * 4 + wave;
    if (pib >= N) return;
    const int point = b * N + pib;

    const float c_off0 = cams[0], c_off1 = cams[1];
    const float inv_h0 = 1.0f / cams[2], inv_h1 = 1.0f / cams[3];
    const float* cam = cams + 4;

    const float* ip = inputs + (size_t)point * 3;
    const float px = ip[0], py = ip[1], pz = ip[2] - 0.8f;

    const float* m0 = cam + (size_t)(b * 3) * 12;
    const float wx = px * m0[0] + py * m0[3] + pz * m0[6] + m0[9];
    const float wy = px * m0[1] + py * m0[4] + pz * m0[7] + m0[10];
    const float wz = px * m0[2] + py * m0[5] + pz * m0[8] + m0[11];

    float  v0[3];
    f32x2  v1[3];
    f32x4  v2[3];

#pragma unroll
    for (int v = 0; v < 3; ++v) {
        const float* m = cam + (size_t)(b * 3 + v) * 12;
        float qx = wx - m[9], qy = wy - m[10], qz = wz - m[11];
        float Xc = m[0] * qx + m[1] * qy + m[2] * qz;
        float Yc = m[3] * qx + m[4] * qy + m[5] * qz;
        float Zc = m[6] * qx + m[7] * qy + m[8] * qz;
        float invZ = 1.0f / Zc;
        float wpix = -248.0f * (Xc * invZ) + c_off0;
        float hpix =  248.0f * (Yc * invZ) + c_off1;
        float gx = fminf(fmaxf(wpix * inv_h0, -1.0f), 1.0f);
        float gy = fminf(fmaxf(hpix * inv_h1, -1.0f), 1.0f);
        Corners cr0 = mk_corners(gx, gy, 56);
        Corners cr1 = mk_corners(gx, gy, 28);
        Corners cr2 = mk_corners(gx, gy, 14);
        const int slice = v * B + b;
        v0[v] = samph<64, 1>(t0 + (size_t)slice * 64 * 3136, cr0, lane);
        v1[v] = samph<128, 2>(t1 + (size_t)slice * 128 * 784, cr1, lane);
        v2[v] = samph<256, 4>(t2 + (size_t)slice * 256 * 196, cr2, lane);
    }

    float* op = out + (size_t)point * 1347;
    if (lane < 3) op[lane] = ip[lane];
    {
        float* basep = op + 3 + lane;
        float mx = fmaxf(v0[0], fmaxf(v0[1], v0[2]));
        float mean = (v0[0] + v0[1] + v0[2]) * (1.0f / 3.0f);
        float dx = v0[0] - mean, dy = v0[1] - mean, dz = v0[2] - mean;
        float sd = sqrtf((dx * dx + dy * dy + dz * dz) * 0.5f);
        basep[0] = mx; basep[448] = mean; basep[896] = sd;
    }
    {
        const int g = 64 + 2 * lane;
        stats3_st<f32x2, 2>(v1[0], v1[1], v1[2],
                            op + 3 + g, op + 451 + g, op + 899 + g);
    }
    {
        const int g = 192 + 4 * lane;
        stats3_st<f32x4, 4>(v2[0], v2[1], v2[2],
                            op + 3 + g, op + 451 + g, op + 899 + g);
    }
}

// ---- last-resort fallback (no workspace): channel-first f32 gathers ----
__device__ __forceinline__ float samp_cf(const float* __restrict__ base,
                                         const Corners& cr, int P, int c) {
    const float* bc = base + (size_t)c * P;
    return cr.w00 * bc[cr.p00] + cr.w10 * bc[cr.p10]
         + cr.w01 * bc[cr.p01] + cr.w11 * bc[cr.p11];
}

__global__ __launch_bounds__(256) void gproj_fallback_kernel(
    const float* __restrict__ f0, const float* __restrict__ f1,
    const float* __restrict__ f2, const float* __restrict__ inputs,
    const float* __restrict__ cams, float* __restrict__ out, int B, int N) {
    const int wave = threadIdx.x >> 6;
    const int lane = threadIdx.x & 63;
    const int point = blockIdx.x * 4 + wave;
    if (point >= B * N) return;
    const int b = point / N;

    const float c_off0 = cams[0], c_off1 = cams[1];
    const float inv_h0 = 1.0f / cams[2], inv_h1 = 1.0f / cams[3];
    const float* cam = cams + 4;

    const float* ip = inputs + (size_t)point * 3;
    const float px = ip[0], py = ip[1], pz = ip[2] - 0.8f;

    const float* m0 = cam + (size_t)(b * 3) * 12;
    const float wx = px * m0[0] + py * m0[3] + pz * m0[6] + m0[9];
    const float wy = px * m0[1] + py * m0[4] + pz * m0[7] + m0[10];
    const float wz = px * m0[2] + py * m0[5] + pz * m0[8] + m0[11];

    float vals[3][7];
#pragma unroll
    for (int v = 0; v < 3; ++v) {
        const float* m = cam + (size_t)(b * 3 + v) * 12;
        float qx = wx - m[9], qy = wy - m[10], qz = wz - m[11];
        float Xc = m[0] * qx + m[1] * qy + m[2] * qz;
        float Yc = m[3] * qx + m[4] * qy + m[5] * qz;
        float Zc = m[6] * qx + m[7] * qy + m[8] * qz;
        float invZ = 1.0f / Zc;
        float wpix = -248.0f * (Xc * invZ) + c_off0;
        float hpix =  248.0f * (Yc * invZ) + c_off1;
        float gx = fminf(fmaxf(wpix * inv_h0, -1.0f), 1.0f);
        float gy = fminf(fmaxf(hpix * inv_h1, -1.0f), 1.0f);
        Corners cr0 = mk_corners(gx, gy, 56);
        Corners cr1 = mk_corners(gx, gy, 28);
        Corners cr2 = mk_corners(gx, gy, 14);
        int slice = v * B + b;
        const float* b0 = f0 + (size_t)slice * 64 * 3136;
        const float* b1 = f1 + (size_t)slice * 128 * 784;
        const float* b2 = f2 + (size_t)slice * 256 * 196;
        vals[v][0] = samp_cf(b0, cr0, 3136, lane);
        vals[v][1] = samp_cf(b1, cr1, 784, lane);
        vals[v][2] = samp_cf(b1, cr1, 784, lane + 64);
        vals[v][3] = samp_cf(b2, cr2, 196, lane);
        vals[v][4] = samp_cf(b2, cr2, 196, lane + 64);
        vals[v][5] = samp_cf(b2, cr2, 196, lane + 128);
        vals[v][6] = samp_cf(b2, cr2, 196, lane + 192);
    }

    float* op = out + (size_t)point * 1347;
    if (lane < 3) op[lane] = ip[lane];
#pragma unroll
    for (int k = 0; k < 7; ++k) {
        float a = vals[0][k], bv = vals[1][k], cv = vals[2][k];
        float mx = fmaxf(a, fmaxf(bv, cv));
        float mean = (a + bv + cv) * (1.0f / 3.0f);
        float da = a - mean, db = bv - mean, dc = cv - mean;
        float sd = sqrtf((da * da + db * db + dc * dc) * 0.5f);
        int g = lane + 64 * k;
        op[3 + g] = mx;
        op[451 + g] = mean;
        op[899 + g] = sd;
    }
}

extern "C" void kernel_launch(void* const* d_in, const int* in_sizes, int n_in,
                              void* d_out, int out_size, void* d_ws, size_t ws_size,
                              hipStream_t stream) {
    const float* feat0 = (const float*)d_in[0];
    const float* feat1 = (const float*)d_in[1];
    const float* feat2 = (const float*)d_in[2];
    const float* inputs = (const float*)d_in[3];
    const float* poses = (const float*)d_in[4];
    const int* resolution = (const int*)d_in[5];
    float* out = (float*)d_out;
    float* ws = (float*)d_ws;

    const int V = 3;
    const int B = in_sizes[4] / (V * 5);
    const int N = in_sizes[3] / (B * 3);
    const int BV = B * V;
    const int total = B * N;

    const size_t cams_elems = 512;                     // f32
    const size_t t0_elems = (size_t)BV * 64 * 3136;    // f16
    const size_t t1_elems = (size_t)BV * 128 * 784;
    const size_t t2_elems = (size_t)BV * 256 * 196;
    const size_t th_elems = t0_elems + t1_elems + t2_elems;
    const size_t corn_elems = (size_t)total * 3 * 24;  // f32
    const size_t need_mid  = cams_elems * sizeof(float) + th_elems * sizeof(f16);
    const size_t need_full = need_mid + corn_elems * sizeof(float);

    const int nbb = (N + 3) / 4;   // blocks per batch
    const int tgrid = BV * (98 * 2 + 25 * 4 + 7 * 8);

    if (ws_size >= need_full) {
        float* corn = ws + cams_elems;
        f16* t0 = (f16*)(corn + corn_elems);
        f16* t1 = t0 + t0_elems;
        f16* t2 = t1 + t1_elems;
        const int cgrid = (total * 3 + 255) / 256;
        prep_kernel<<<tgrid + cgrid, 256, 0, stream>>>(
            feat0, feat1, feat2, t0, t1, t2, inputs, poses, resolution,
            corn, B, N, BV, tgrid);
        gproj_main_kernel<<<B * nbb, 256, 0, stream>>>(t0, t1, t2, inputs, corn, out, B, N);
    } else if (ws_size >= need_mid) {
        setup_cams_kernel<<<1, 64, 0, stream>>>(poses, resolution, ws, BV);
        f16* t0 = (f16*)(ws + cams_elems);
        f16* t1 = t0 + t0_elems;
        f16* t2 = t1 + t1_elems;
        dim3 tblk(32, 8);
        // reuse prep_kernel's transpose range only (cgrid=0 via tgrid arg)
        prep_kernel<<<tgrid, 256, 0, stream>>>(
            feat0, feat1, feat2, t0, t1, t2, inputs, poses, resolution,
            /*corn=*/ws, B, N, BV, tgrid);
        gproj_fused_kernel<<<B * nbb, 256, 0, stream>>>(t0, t1, t2, inputs, ws, out, B, N);
    } else {
        setup_cams_kernel<<<1, 64, 0, stream>>>(poses, resolution, ws, BV);
        gproj_fallback_kernel<<<(total + 3) / 4, 256, 0, stream>>>(
            feat0, feat1, feat2, inputs, ws, out, B, N);
    }
}

// Round 9
// 95.456 us; speedup vs baseline: 2.4134x; 1.0619x over previous
//
#include <hip/hip_runtime.h>
#include <cstdint>
#include <cmath>

// ---------------------------------------------------------------------------
// GProjection: project B*N points into V=3 views, bilinear-sample 3 feature
// pyramids (64@56x56, 128@28x28, 256@14x14 -> 448 ch), reduce max/mean/std
// over views. Output [B,N,3+3*448] f32.
//
// R9: packed LDS staging (row r at offset r*1347, mirrors the output region).
//  - sweep: one aligned ds_read_b128 per float4 (conflict-free, 1024B/wave)
//    + nt global store; no per-element row-select VALU (was ~100 VALU/thread
//    + 8-way bank conflicts on scalar stride-4 reads).
//  - stats phase writes LDS as scalar b32 (lane-stride 1/2/4 -> <=1.58x).
// prep_kernel (transpose U corners, R8), f16 channel-last feats (R3),
// XCD-batch pinning (R2), scalar-hoisted corner loads (R5).
// ---------------------------------------------------------------------------

typedef float f32x2 __attribute__((ext_vector_type(2)));
typedef float f32x4 __attribute__((ext_vector_type(4)));
typedef _Float16 f16;
typedef _Float16 f16x2 __attribute__((ext_vector_type(2)));
typedef _Float16 f16x4 __attribute__((ext_vector_type(4)));

// ---- camera matrix from a pose row ----
__device__ __forceinline__ void make_cam(const float* __restrict__ p, float* c) {
    const float d = 0.017453292519943295f;  // pi/180
    float theta = p[0] * d;
    float elr   = p[1] * d;
    float dist  = p[3];
    float st = sinf(theta), ct = cosf(theta);
    float se = sinf(elr),   ce = cosf(elr);
    float camy = dist * se;
    float lens = dist * ce;
    float camx = lens * ct;
    float camz = lens * st;
    float Zx = camx, Zy = camy, Zz = camz;
    float Yx = -camy * ct, Yy = lens, Yz = -camy * st;  // cos/sin(theta+pi)
    float Xx = Yy * Zz - Yz * Zy;
    float Xy = Yz * Zx - Yx * Zz;
    float Xz = Yx * Zy - Yy * Zx;
    float rx = 1.0f / sqrtf(Xx*Xx + Xy*Xy + Xz*Xz);
    float ry = 1.0f / sqrtf(Yx*Yx + Yy*Yy + Yz*Yz);
    float rz = 1.0f / sqrtf(Zx*Zx + Zy*Zy + Zz*Zz);
    c[0] = Xx*rx; c[1] = Xy*rx; c[2] = Xz*rx;
    c[3] = Yx*ry; c[4] = Yy*ry; c[5] = Yz*ry;
    c[6] = Zx*rz; c[7] = Zy*rz; c[8] = Zz*rz;
    c[9] = camx; c[10] = camy; c[11] = camz;
}

__global__ void setup_cams_kernel(const float* __restrict__ poses,
                                  const int* __restrict__ resolution,
                                  float* __restrict__ ws, int BV) {
    int t = blockIdx.x * blockDim.x + threadIdx.x;
    if (t == 0) {
        float h0 = ((float)resolution[0] - 1.0f) * 0.5f;
        float h1 = ((float)resolution[1] - 1.0f) * 0.5f;
        ws[0] = 111.5f - h0;   // c_off0
        ws[1] = 111.5f - h1;   // c_off1
        ws[2] = h0;            // half_res0
        ws[3] = h1;            // half_res1
    }
    if (t < BV) make_cam(poses + (size_t)t * 5, ws + 4 + (size_t)t * 12);
}

struct Corners {
    int p00, p10, p01, p11;
    float w00, w10, w01, w11;
};

__device__ __forceinline__ Corners mk_corners(float gx, float gy, int S) {
    // torch grid_sample: bilinear, zeros padding, align_corners=False
    float x = ((gx + 1.0f) * (float)S - 1.0f) * 0.5f;
    float y = ((gy + 1.0f) * (float)S - 1.0f) * 0.5f;
    float x0f = floorf(x), y0f = floorf(y);
    float wx1 = x - x0f, wy1 = y - y0f;
    float wx0 = 1.0f - wx1, wy0 = 1.0f - wy1;
    int x0 = (int)x0f, y0 = (int)y0f;
    int x1 = x0 + 1, y1 = y0 + 1;
    bool vx0 = (x0 >= 0) && (x0 <= S - 1);
    bool vx1 = (x1 >= 0) && (x1 <= S - 1);
    bool vy0 = (y0 >= 0) && (y0 <= S - 1);
    bool vy1 = (y1 >= 0) && (y1 <= S - 1);
    int xi0 = min(max(x0, 0), S - 1);
    int xi1 = min(max(x1, 0), S - 1);
    int yi0 = min(max(y0, 0), S - 1);
    int yi1 = min(max(y1, 0), S - 1);
    Corners c;
    c.p00 = yi0 * S + xi0;
    c.p10 = yi0 * S + xi1;
    c.p01 = yi1 * S + xi0;
    c.p11 = yi1 * S + xi1;
    c.w00 = wx0 * wy0 * ((vx0 && vy0) ? 1.0f : 0.0f);
    c.w10 = wx1 * wy0 * ((vx1 && vy0) ? 1.0f : 0.0f);
    c.w01 = wx0 * wy1 * ((vx0 && vy1) ? 1.0f : 0.0f);
    c.w11 = wx1 * wy1 * ((vx1 && vy1) ? 1.0f : 0.0f);
    return c;
}

// ---- prep kernel: transpose tiles UNION corner blocks, one dispatch ----
__global__ __launch_bounds__(256) void prep_kernel(
    const float* __restrict__ f0, const float* __restrict__ f1,
    const float* __restrict__ f2, f16* __restrict__ t0, f16* __restrict__ t1,
    f16* __restrict__ t2, const float* __restrict__ inputs,
    const float* __restrict__ poses, const int* __restrict__ resolution,
    float* __restrict__ corn, int B, int N, int BV, int tgrid) {
    __shared__ float tile[32][33];
    const int bid = blockIdx.x;
    if (bid < tgrid) {
        // ---------------- transpose part ----------------
        const int nb0 = 98 * 2 * BV;
        const int nb1 = 25 * 4 * BV;
        const float* src; f16* dst; int C, P, tP, local;
        if (bid < nb0)            { src = f0; dst = t0; C = 64;  P = 3136; tP = 98; local = bid; }
        else if (bid < nb0 + nb1) { src = f1; dst = t1; C = 128; P = 784;  tP = 25; local = bid - nb0; }
        else                      { src = f2; dst = t2; C = 256; P = 196;  tP = 7;  local = bid - nb0 - nb1; }
        int per = tP * (C >> 5);
        int slice = local / per;
        int rem = local - slice * per;
        int cy = rem / tP;
        int cx = rem - cy * tP;
        const float* s = src + (size_t)slice * C * P;
        f16* d = dst + (size_t)slice * C * P;
        int p0 = cx * 32, c0 = cy * 32;
        int tx = threadIdx.x & 31, ty = threadIdx.x >> 5;
#pragma unroll
        for (int i = 0; i < 32; i += 8) {
            int c = c0 + ty + i, p = p0 + tx;
            if (p < P) tile[ty + i][tx] = s[(size_t)c * P + p];
        }
        __syncthreads();
#pragma unroll
        for (int i = 0; i < 32; i += 8) {
            int p = p0 + ty + i, c = c0 + tx;
            if (p < P) d[(size_t)p * C + c] = (f16)tile[tx][ty + i];
        }
    } else {
        // ---------------- corners part (cams inline) ----------------
        int t = (bid - tgrid) * 256 + threadIdx.x;
        if (t >= B * N * 3) return;
        int point = t / 3;
        int v = t - point * 3;
        int b = point / N;

        float h0 = ((float)resolution[0] - 1.0f) * 0.5f;
        float h1 = ((float)resolution[1] - 1.0f) * 0.5f;
        float c_off0 = 111.5f - h0, c_off1 = 111.5f - h1;
        float inv_h0 = 1.0f / h0, inv_h1 = 1.0f / h1;

        float cm0[12], cmv[12];
        make_cam(poses + (size_t)(b * 3) * 5, cm0);
        make_cam(poses + (size_t)(b * 3 + v) * 5, cmv);

        const float* ip = inputs + (size_t)point * 3;
        const float px = ip[0], py = ip[1], pz = ip[2] - 0.8f;  // + MESH_POS

        const float wx = px * cm0[0] + py * cm0[3] + pz * cm0[6] + cm0[9];
        const float wy = px * cm0[1] + py * cm0[4] + pz * cm0[7] + cm0[10];
        const float wz = px * cm0[2] + py * cm0[5] + pz * cm0[8] + cm0[11];

        float qx = wx - cmv[9], qy = wy - cmv[10], qz = wz - cmv[11];
        float Xc = cmv[0] * qx + cmv[1] * qy + cmv[2] * qz;
        float Yc = cmv[3] * qx + cmv[4] * qy + cmv[5] * qz;
        float Zc = cmv[6] * qx + cmv[7] * qy + cmv[8] * qz;
        float invZ = 1.0f / Zc;
        float wpix = -248.0f * (Xc * invZ) + c_off0;
        float hpix =  248.0f * (Yc * invZ) + c_off1;
        float gx = fminf(fmaxf(wpix * inv_h0, -1.0f), 1.0f);
        float gy = fminf(fmaxf(hpix * inv_h1, -1.0f), 1.0f);

        float* o = corn + (size_t)t * 24;
        const int S[3] = {56, 28, 14};
        const int CB[3] = {64 * 2, 128 * 2, 256 * 2};  // row bytes (f16)
#pragma unroll
        for (int lvl = 0; lvl < 3; ++lvl) {
            Corners cr = mk_corners(gx, gy, S[lvl]);
            o[lvl * 8 + 0] = __int_as_float(cr.p00 * CB[lvl]);
            o[lvl * 8 + 1] = __int_as_float(cr.p10 * CB[lvl]);
            o[lvl * 8 + 2] = __int_as_float(cr.p01 * CB[lvl]);
            o[lvl * 8 + 3] = __int_as_float(cr.p11 * CB[lvl]);
            o[lvl * 8 + 4] = cr.w00;
            o[lvl * 8 + 5] = cr.w10;
            o[lvl * 8 + 6] = cr.w01;
            o[lvl * 8 + 7] = cr.w11;
        }
    }
}

template <int VEC> struct VecOf;
template <> struct VecOf<1> { using T = float; };
template <> struct VecOf<2> { using T = f32x2; };
template <> struct VecOf<4> { using T = f32x4; };
template <int VEC> struct F16VecOf;
template <> struct F16VecOf<1> { using T = f16; };
template <> struct F16VecOf<2> { using T = f16x2; };
template <> struct F16VecOf<4> { using T = f16x4; };

template <int VEC>
__device__ __forceinline__ typename VecOf<VEC>::T
gather4(const f16* __restrict__ base, const int4 off, const float4 w, int lane) {
    using HV = typename F16VecOf<VEC>::T;
    using FV = typename VecOf<VEC>::T;
    const char* cb = (const char*)base;
    const int lo = lane * (VEC * 2);
    HV h00 = *(const HV*)(cb + off.x + lo);
    HV h10 = *(const HV*)(cb + off.y + lo);
    HV h01 = *(const HV*)(cb + off.z + lo);
    HV h11 = *(const HV*)(cb + off.w + lo);
    FV a00, a10, a01, a11;
    if constexpr (VEC == 1) {
        a00 = (float)h00; a10 = (float)h10; a01 = (float)h01; a11 = (float)h11;
    } else {
        a00 = __builtin_convertvector(h00, FV);
        a10 = __builtin_convertvector(h10, FV);
        a01 = __builtin_convertvector(h01, FV);
        a11 = __builtin_convertvector(h11, FV);
    }
    return w.x * a00 + w.y * a10 + w.z * a01 + w.w * a11;
}

template <typename VecT, int VEC>
__device__ __forceinline__ void stats3(VecT a, VecT b, VecT c,
                                       VecT* omx, VecT* ome, VecT* osd) {
    const float* pa = (const float*)&a;
    const float* pb = (const float*)&b;
    const float* pc = (const float*)&c;
    float* qx = (float*)omx; float* qe = (float*)ome; float* qs = (float*)osd;
#pragma unroll
    for (int j = 0; j < VEC; ++j) {
        float x = pa[j], y = pb[j], z = pc[j];
        float m = fmaxf(x, fmaxf(y, z));
        float mean = (x + y + z) * (1.0f / 3.0f);
        float dx = x - mean, dy = y - mean, dz = z - mean;
        float s = sqrtf((dx * dx + dy * dy + dz * dz) * 0.5f);  // ddof=1
        qx[j] = m; qe[j] = mean; qs[j] = s;
    }
}

// Main kernel: 4 points/block, PACKED LDS staging (row r at r*1347 — mirrors
// the output region exactly), scalar b32 stats writes (lane-stride 1/2/4),
// sweep = aligned ds_read_b128 + nt store, zero index math.
// b = blockIdx.x % B: XCD-batch pinning.
__global__ __launch_bounds__(256) void gproj_main_kernel(
    const f16* __restrict__ t0, const f16* __restrict__ t1,
    const f16* __restrict__ t2, const float* __restrict__ inputs,
    const float* __restrict__ corn, float* __restrict__ out, int B, int N) {
    __shared__ alignas(16) float sb[4 * 1347];
    const int wave = threadIdx.x >> 6;
    const int lane = threadIdx.x & 63;
    const int b = blockIdx.x % B;
    const int pb = (blockIdx.x / B) * 4;
    const int pib = pb + wave;
    const bool valid = pib < N;

    if (valid) {
        const int point = b * N + pib;
        const int pu = __builtin_amdgcn_readfirstlane(point);
        const int bu = __builtin_amdgcn_readfirstlane(b);
        const float* ip = inputs + (size_t)point * 3;

        float  v0[3];
        f32x2  v1[3];
        f32x4  v2[3];

#pragma unroll
        for (int v = 0; v < 3; ++v) {
            const float* cp = corn + (size_t)(pu * 3 + v) * 24;
            const int slice = v * B + bu;
            const f16* b0 = t0 + (size_t)slice * 64 * 3136;
            const f16* b1 = t1 + (size_t)slice * 128 * 784;
            const f16* b2 = t2 + (size_t)slice * 256 * 196;

            int4   o0 = *(const int4*)(cp);
            float4 w0 = *(const float4*)(cp + 4);
            int4   o1 = *(const int4*)(cp + 8);
            float4 w1 = *(const float4*)(cp + 12);
            int4   o2 = *(const int4*)(cp + 16);
            float4 w2 = *(const float4*)(cp + 20);

            v0[v] = gather4<1>(b0, o0, w0, lane);
            v1[v] = gather4<2>(b1, o1, w1, lane);
            v2[v] = gather4<4>(b2, o2, w2, lane);
        }

        float* row = sb + wave * 1347;   // packed: mirrors output row
        if (lane < 3) row[lane] = ip[lane];
        {   // level0: scalar, lane-stride 1 (conflict-free)
            float mx = fmaxf(v0[0], fmaxf(v0[1], v0[2]));
            float mean = (v0[0] + v0[1] + v0[2]) * (1.0f / 3.0f);
            float dx = v0[0] - mean, dy = v0[1] - mean, dz = v0[2] - mean;
            float sd = sqrtf((dx * dx + dy * dy + dz * dz) * 0.5f);
            row[3 + lane] = mx;
            row[451 + lane] = mean;
            row[899 + lane] = sd;
        }
        {   // level1: scalar b32 pairs, lane-stride 2 (free per m136)
            f32x2 mx, me, sd;
            stats3<f32x2, 2>(v1[0], v1[1], v1[2], &mx, &me, &sd);
            const int g = 64 + 2 * lane;
            row[3 + g] = mx.x;   row[3 + g + 1] = mx.y;
            row[451 + g] = me.x; row[451 + g + 1] = me.y;
            row[899 + g] = sd.x; row[899 + g + 1] = sd.y;
        }
        {   // level2: scalar b32 x4, lane-stride 4 (~1.58x, bounded)
            f32x4 mx, me, sd;
            stats3<f32x4, 4>(v2[0], v2[1], v2[2], &mx, &me, &sd);
            const int g = 192 + 4 * lane;
#pragma unroll
            for (int e = 0; e < 4; ++e) {
                row[3 + g + e] = mx[e];
                row[451 + g + e] = me[e];
                row[899 + g + e] = sd[e];
            }
        }
    }
    __syncthreads();

    // sweep: packed LDS == output region; aligned b128 reads, nt stores
    const int nvalid = min(N - pb, 4);
    const int len = nvalid * 1347;
    float* gout = out + (size_t)(b * N + pb) * 1347;
    const int len4 = len & ~3;
    for (int j = threadIdx.x * 4; j < len4; j += 1024) {
        f32x4 vv = *(const f32x4*)(sb + j);
        __builtin_nontemporal_store(vv, (f32x4*)(gout + j));
    }
    if ((len & 3) && threadIdx.x == 0) {
        for (int jj = len4; jj < len; ++jj) gout[jj] = sb[jj];
    }
}

// ---- mid-fallback: fused kernel (inline corners), f16 feats ----
template <int C, int VEC>
__device__ __forceinline__ typename VecOf<VEC>::T
samph(const f16* __restrict__ base, const Corners& cr, int lane) {
    using HV = typename F16VecOf<VEC>::T;
    using FV = typename VecOf<VEC>::T;
    const HV* r00 = (const HV*)(base + (size_t)cr.p00 * C);
    const HV* r10 = (const HV*)(base + (size_t)cr.p10 * C);
    const HV* r01 = (const HV*)(base + (size_t)cr.p01 * C);
    const HV* r11 = (const HV*)(base + (size_t)cr.p11 * C);
    HV h00 = r00[lane], h10 = r10[lane], h01 = r01[lane], h11 = r11[lane];
    FV a00, a10, a01, a11;
    if constexpr (VEC == 1) {
        a00 = (float)h00; a10 = (float)h10; a01 = (float)h01; a11 = (float)h11;
    } else {
        a00 = __builtin_convertvector(h00, FV);
        a10 = __builtin_convertvector(h10, FV);
        a01 = __builtin_convertvector(h01, FV);
        a11 = __builtin_convertvector(h11, FV);
    }
    return cr.w00 * a00 + cr.w10 * a10 + cr.w01 * a01 + cr.w11 * a11;
}

template <typename VecT, int VEC>
__device__ __forceinline__ void stats3_st(VecT a, VecT b, VecT c,
                                          float* pmx, float* pme, float* psd) {
    VecT mx, me, sd;
    stats3<VecT, VEC>(a, b, c, &mx, &me, &sd);
    *(VecT*)pmx = mx; *(VecT*)pme = me; *(VecT*)psd = sd;
}

__global__ __launch_bounds__(256) void gproj_fused_kernel(
    const f16* __restrict__ t0, const f16* __restrict__ t1,
    const f16* __restrict__ t2, const float* __restrict__ inputs,
    const float* __restrict__ cams, float* __restrict__ out, int B, int N) {
    const int wave = threadIdx.x >> 6;
    const int lane = threadIdx.x & 63;
    const int b = blockIdx.x % B;
    const int pib = (blockIdx.x / B) * 4 + wave;
    if (pib >= N) return;
    const int point = b * N + pib;

    const float c_off0 = cams[0], c_off1 = cams[1];
    const float inv_h0 = 1.0f / cams[2], inv_h1 = 1.0f / cams[3];
    const float* cam = cams + 4;

    const float* ip = inputs + (size_t)point * 3;
    const float px = ip[0], py = ip[1], pz = ip[2] - 0.8f;

    const float* m0 = cam + (size_t)(b * 3) * 12;
    const float wx = px * m0[0] + py * m0[3] + pz * m0[6] + m0[9];
    const float wy = px * m0[1] + py * m0[4] + pz * m0[7] + m0[10];
    const float wz = px * m0[2] + py * m0[5] + pz * m0[8] + m0[11];

    float  v0[3];
    f32x2  v1[3];
    f32x4  v2[3];

#pragma unroll
    for (int v = 0; v < 3; ++v) {
        const float* m = cam + (size_t)(b * 3 + v) * 12;
        float qx = wx - m[9], qy = wy - m[10], qz = wz - m[11];
        float Xc = m[0] * qx + m[1] * qy + m[2] * qz;
        float Yc = m[3] * qx + m[4] * qy + m[5] * qz;
        float Zc = m[6] * qx + m[7] * qy + m[8] * qz;
        float invZ = 1.0f / Zc;
        float wpix = -248.0f * (Xc * invZ) + c_off0;
        float hpix =  248.0f * (Yc * invZ) + c_off1;
        float gx = fminf(fmaxf(wpix * inv_h0, -1.0f), 1.0f);
        float gy = fminf(fmaxf(hpix * inv_h1, -1.0f), 1.0f);
        Corners cr0 = mk_corners(gx, gy, 56);
        Corners cr1 = mk_corners(gx, gy, 28);
        Corners cr2 = mk_corners(gx, gy, 14);
        const int slice = v * B + b;
        v0[v] = samph<64, 1>(t0 + (size_t)slice * 64 * 3136, cr0, lane);
        v1[v] = samph<128, 2>(t1 + (size_t)slice * 128 * 784, cr1, lane);
        v2[v] = samph<256, 4>(t2 + (size_t)slice * 256 * 196, cr2, lane);
    }

    float* op = out + (size_t)point * 1347;
    if (lane < 3) op[lane] = ip[lane];
    {
        float* basep = op + 3 + lane;
        float mx = fmaxf(v0[0], fmaxf(v0[1], v0[2]));
        float mean = (v0[0] + v0[1] + v0[2]) * (1.0f / 3.0f);
        float dx = v0[0] - mean, dy = v0[1] - mean, dz = v0[2] - mean;
        float sd = sqrtf((dx * dx + dy * dy + dz * dz) * 0.5f);
        basep[0] = mx; basep[448] = mean; basep[896] = sd;
    }
    {
        const int g = 64 + 2 * lane;
        stats3_st<f32x2, 2>(v1[0], v1[1], v1[2],
                            op + 3 + g, op + 451 + g, op + 899 + g);
    }
    {
        const int g = 192 + 4 * lane;
        stats3_st<f32x4, 4>(v2[0], v2[1], v2[2],
                            op + 3 + g, op + 451 + g, op + 899 + g);
    }
}

// ---- last-resort fallback (no workspace): channel-first f32 gathers ----
__device__ __forceinline__ float samp_cf(const float* __restrict__ base,
                                         const Corners& cr, int P, int c) {
    const float* bc = base + (size_t)c * P;
    return cr.w00 * bc[cr.p00] + cr.w10 * bc[cr.p10]
         + cr.w01 * bc[cr.p01] + cr.w11 * bc[cr.p11];
}

__global__ __launch_bounds__(256) void gproj_fallback_kernel(
    const float* __restrict__ f0, const float* __restrict__ f1,
    const float* __restrict__ f2, const float* __restrict__ inputs,
    const float* __restrict__ cams, float* __restrict__ out, int B, int N) {
    const int wave = threadIdx.x >> 6;
    const int lane = threadIdx.x & 63;
    const int point = blockIdx.x * 4 + wave;
    if (point >= B * N) return;
    const int b = point / N;

    const float c_off0 = cams[0], c_off1 = cams[1];
    const float inv_h0 = 1.0f / cams[2], inv_h1 = 1.0f / cams[3];
    const float* cam = cams + 4;

    const float* ip = inputs + (size_t)point * 3;
    const float px = ip[0], py = ip[1], pz = ip[2] - 0.8f;

    const float* m0 = cam + (size_t)(b * 3) * 12;
    const float wx = px * m0[0] + py * m0[3] + pz * m0[6] + m0[9];
    const float wy = px * m0[1] + py * m0[4] + pz * m0[7] + m0[10];
    const float wz = px * m0[2] + py * m0[5] + pz * m0[8] + m0[11];

    float vals[3][7];
#pragma unroll
    for (int v = 0; v < 3; ++v) {
        const float* m = cam + (size_t)(b * 3 + v) * 12;
        float qx = wx - m[9], qy = wy - m[10], qz = wz - m[11];
        float Xc = m[0] * qx + m[1] * qy + m[2] * qz;
        float Yc = m[3] * qx + m[4] * qy + m[5] * qz;
        float Zc = m[6] * qx + m[7] * qy + m[8] * qz;
        float invZ = 1.0f / Zc;
        float wpix = -248.0f * (Xc * invZ) + c_off0;
        float hpix =  248.0f * (Yc * invZ) + c_off1;
        float gx = fminf(fmaxf(wpix * inv_h0, -1.0f), 1.0f);
        float gy = fminf(fmaxf(hpix * inv_h1, -1.0f), 1.0f);
        Corners cr0 = mk_corners(gx, gy, 56);
        Corners cr1 = mk_corners(gx, gy, 28);
        Corners cr2 = mk_corners(gx, gy, 14);
        int slice = v * B + b;
        const float* b0 = f0 + (size_t)slice * 64 * 3136;
        const float* b1 = f1 + (size_t)slice * 128 * 784;
        const float* b2 = f2 + (size_t)slice * 256 * 196;
        vals[v][0] = samp_cf(b0, cr0, 3136, lane);
        vals[v][1] = samp_cf(b1, cr1, 784, lane);
        vals[v][2] = samp_cf(b1, cr1, 784, lane + 64);
        vals[v][3] = samp_cf(b2, cr2, 196, lane);
        vals[v][4] = samp_cf(b2, cr2, 196, lane + 64);
        vals[v][5] = samp_cf(b2, cr2, 196, lane + 128);
        vals[v][6] = samp_cf(b2, cr2, 196, lane + 192);
    }

    float* op = out + (size_t)point * 1347;
    if (lane < 3) op[lane] = ip[lane];
#pragma unroll
    for (int k = 0; k < 7; ++k) {
        float a = vals[0][k], bv = vals[1][k], cv = vals[2][k];
        float mx = fmaxf(a, fmaxf(bv, cv));
        float mean = (a + bv + cv) * (1.0f / 3.0f);
        float da = a - mean, db = bv - mean, dc = cv - mean;
        float sd = sqrtf((da * da + db * db + dc * dc) * 0.5f);
        int g = lane + 64 * k;
        op[3 + g] = mx;
        op[451 + g] = mean;
        op[899 + g] = sd;
    }
}

extern "C" void kernel_launch(void* const* d_in, const int* in_sizes, int n_in,
                              void* d_out, int out_size, void* d_ws, size_t ws_size,
                              hipStream_t stream) {
    const float* feat0 = (const float*)d_in[0];
    const float* feat1 = (const float*)d_in[1];
    const float* feat2 = (const float*)d_in[2];
    const float* inputs = (const float*)d_in[3];
    const float* poses = (const float*)d_in[4];
    const int* resolution = (const int*)d_in[5];
    float* out = (float*)d_out;
    float* ws = (float*)d_ws;

    const int V = 3;
    const int B = in_sizes[4] / (V * 5);
    const int N = in_sizes[3] / (B * 3);
    const int BV = B * V;
    const int total = B * N;

    const size_t cams_elems = 512;                     // f32
    const size_t t0_elems = (size_t)BV * 64 * 3136;    // f16
    const size_t t1_elems = (size_t)BV * 128 * 784;
    const size_t t2_elems = (size_t)BV * 256 * 196;
    const size_t th_elems = t0_elems + t1_elems + t2_elems;
    const size_t corn_elems = (size_t)total * 3 * 24;  // f32
    const size_t need_mid  = cams_elems * sizeof(float) + th_elems * sizeof(f16);
    const size_t need_full = need_mid + corn_elems * sizeof(float);

    const int nbb = (N + 3) / 4;   // blocks per batch
    const int tgrid = BV * (98 * 2 + 25 * 4 + 7 * 8);

    if (ws_size >= need_full) {
        float* corn = ws + cams_elems;
        f16* t0 = (f16*)(corn + corn_elems);
        f16* t1 = t0 + t0_elems;
        f16* t2 = t1 + t1_elems;
        const int cgrid = (total * 3 + 255) / 256;
        prep_kernel<<<tgrid + cgrid, 256, 0, stream>>>(
            feat0, feat1, feat2, t0, t1, t2, inputs, poses, resolution,
            corn, B, N, BV, tgrid);
        gproj_main_kernel<<<B * nbb, 256, 0, stream>>>(t0, t1, t2, inputs, corn, out, B, N);
    } else if (ws_size >= need_mid) {
        setup_cams_kernel<<<1, 64, 0, stream>>>(poses, resolution, ws, BV);
        f16* t0 = (f16*)(ws + cams_elems);
        f16* t1 = t0 + t0_elems;
        f16* t2 = t1 + t1_elems;
        prep_kernel<<<tgrid, 256, 0, stream>>>(
            feat0, feat1, feat2, t0, t1, t2, inputs, poses, resolution,
            /*corn=*/ws, B, N, BV, tgrid);
        gproj_fused_kernel<<<B * nbb, 256, 0, stream>>>(t0, t1, t2, inputs, ws, out, B, N);
    } else {
        setup_cams_kernel<<<1, 64, 0, stream>>>(poses, resolution, ws, BV);
        gproj_fallback_kernel<<<(total + 3) / 4, 256, 0, stream>>>(
            feat0, feat1, feat2, inputs, ws, out, B, N);
    }
}

// Round 10
// 88.131 us; speedup vs baseline: 2.6141x; 1.0831x over previous
//
#include <hip/hip_runtime.h>
#include <cstdint>
#include <cmath>

// ---------------------------------------------------------------------------
// GProjection: project B*N points into V=3 views, bilinear-sample 3 feature
// pyramids (64@56x56, 128@28x28, 256@14x14 -> 448 ch), reduce max/mean/std
// over views. Output [B,N,3+3*448] f32.
//
// R10:
//  - prep corner section: 24 cams computed ONCE per block into LDS (was
//    2x make_cam per thread, ~120 VALU incl. transcendentals).
//  - corn slots packed to 16B/(point,view,level): u16x4 pixel idx + f16x4
//    weights (row strides 128/256/512B = shifts 7/8/9). corn 19 -> 9.4 MB;
//    main loads one 16B wave-uniform slot per level.
// Carried: packed-LDS staging + aligned b128 sweep (R9), prep union kernel
// (R8), LDS-staged stats (R7), corners precompute (R5), f16 channel-last
// feats (R3), XCD-batch pinning + nt stores (R2).
// ---------------------------------------------------------------------------

typedef float f32x2 __attribute__((ext_vector_type(2)));
typedef float f32x4 __attribute__((ext_vector_type(4)));
typedef _Float16 f16;
typedef _Float16 f16x2 __attribute__((ext_vector_type(2)));
typedef _Float16 f16x4 __attribute__((ext_vector_type(4)));

// ---- camera matrix from a pose row ----
__device__ __forceinline__ void make_cam(const float* __restrict__ p, float* c) {
    const float d = 0.017453292519943295f;  // pi/180
    float theta = p[0] * d;
    float elr   = p[1] * d;
    float dist  = p[3];
    float st = sinf(theta), ct = cosf(theta);
    float se = sinf(elr),   ce = cosf(elr);
    float camy = dist * se;
    float lens = dist * ce;
    float camx = lens * ct;
    float camz = lens * st;
    float Zx = camx, Zy = camy, Zz = camz;
    float Yx = -camy * ct, Yy = lens, Yz = -camy * st;  // cos/sin(theta+pi)
    float Xx = Yy * Zz - Yz * Zy;
    float Xy = Yz * Zx - Yx * Zz;
    float Xz = Yx * Zy - Yy * Zx;
    float rx = 1.0f / sqrtf(Xx*Xx + Xy*Xy + Xz*Xz);
    float ry = 1.0f / sqrtf(Yx*Yx + Yy*Yy + Yz*Yz);
    float rz = 1.0f / sqrtf(Zx*Zx + Zy*Zy + Zz*Zz);
    c[0] = Xx*rx; c[1] = Xy*rx; c[2] = Xz*rx;
    c[3] = Yx*ry; c[4] = Yy*ry; c[5] = Yz*ry;
    c[6] = Zx*rz; c[7] = Zy*rz; c[8] = Zz*rz;
    c[9] = camx; c[10] = camy; c[11] = camz;
}

__global__ void setup_cams_kernel(const float* __restrict__ poses,
                                  const int* __restrict__ resolution,
                                  float* __restrict__ ws, int BV) {
    int t = blockIdx.x * blockDim.x + threadIdx.x;
    if (t == 0) {
        float h0 = ((float)resolution[0] - 1.0f) * 0.5f;
        float h1 = ((float)resolution[1] - 1.0f) * 0.5f;
        ws[0] = 111.5f - h0;   // c_off0
        ws[1] = 111.5f - h1;   // c_off1
        ws[2] = h0;            // half_res0
        ws[3] = h1;            // half_res1
    }
    if (t < BV) make_cam(poses + (size_t)t * 5, ws + 4 + (size_t)t * 12);
}

struct Corners {
    int p00, p10, p01, p11;
    float w00, w10, w01, w11;
};

__device__ __forceinline__ Corners mk_corners(float gx, float gy, int S) {
    // torch grid_sample: bilinear, zeros padding, align_corners=False
    float x = ((gx + 1.0f) * (float)S - 1.0f) * 0.5f;
    float y = ((gy + 1.0f) * (float)S - 1.0f) * 0.5f;
    float x0f = floorf(x), y0f = floorf(y);
    float wx1 = x - x0f, wy1 = y - y0f;
    float wx0 = 1.0f - wx1, wy0 = 1.0f - wy1;
    int x0 = (int)x0f, y0 = (int)y0f;
    int x1 = x0 + 1, y1 = y0 + 1;
    bool vx0 = (x0 >= 0) && (x0 <= S - 1);
    bool vx1 = (x1 >= 0) && (x1 <= S - 1);
    bool vy0 = (y0 >= 0) && (y0 <= S - 1);
    bool vy1 = (y1 >= 0) && (y1 <= S - 1);
    int xi0 = min(max(x0, 0), S - 1);
    int xi1 = min(max(x1, 0), S - 1);
    int yi0 = min(max(y0, 0), S - 1);
    int yi1 = min(max(y1, 0), S - 1);
    Corners c;
    c.p00 = yi0 * S + xi0;
    c.p10 = yi0 * S + xi1;
    c.p01 = yi1 * S + xi0;
    c.p11 = yi1 * S + xi1;
    c.w00 = wx0 * wy0 * ((vx0 && vy0) ? 1.0f : 0.0f);
    c.w10 = wx1 * wy0 * ((vx1 && vy0) ? 1.0f : 0.0f);
    c.w01 = wx0 * wy1 * ((vx0 && vy1) ? 1.0f : 0.0f);
    c.w11 = wx1 * wy1 * ((vx1 && vy1) ? 1.0f : 0.0f);
    return c;
}

__device__ __forceinline__ unsigned pack_u16(int a, int b) {
    return (unsigned)(a & 0xffff) | ((unsigned)b << 16);
}
__device__ __forceinline__ unsigned pack_f16(float a, float b) {
    f16x2 h; h.x = (f16)a; h.y = (f16)b;
    return __builtin_bit_cast(unsigned, h);
}

// ---- prep kernel: transpose tiles UNION corner blocks, one dispatch ----
// corn slot layout per (point,view): 3 x uint4 {o00|o10<<16, o01|o11<<16,
// h2(w00,w10), h2(w01,w11)} -> 48B.
__global__ __launch_bounds__(256) void prep_kernel(
    const float* __restrict__ f0, const float* __restrict__ f1,
    const float* __restrict__ f2, f16* __restrict__ t0, f16* __restrict__ t1,
    f16* __restrict__ t2, const float* __restrict__ inputs,
    const float* __restrict__ poses, const int* __restrict__ resolution,
    unsigned* __restrict__ corn, int B, int N, int BV, int tgrid) {
    __shared__ float tile[32][33];
    __shared__ float lds_cam[24 * 12];
    const int bid = blockIdx.x;
    if (bid < tgrid) {
        // ---------------- transpose part ----------------
        const int nb0 = 98 * 2 * BV;
        const int nb1 = 25 * 4 * BV;
        const float* src; f16* dst; int C, P, tP, local;
        if (bid < nb0)            { src = f0; dst = t0; C = 64;  P = 3136; tP = 98; local = bid; }
        else if (bid < nb0 + nb1) { src = f1; dst = t1; C = 128; P = 784;  tP = 25; local = bid - nb0; }
        else                      { src = f2; dst = t2; C = 256; P = 196;  tP = 7;  local = bid - nb0 - nb1; }
        int per = tP * (C >> 5);
        int slice = local / per;
        int rem = local - slice * per;
        int cy = rem / tP;
        int cx = rem - cy * tP;
        const float* s = src + (size_t)slice * C * P;
        f16* d = dst + (size_t)slice * C * P;
        int p0 = cx * 32, c0 = cy * 32;
        int tx = threadIdx.x & 31, ty = threadIdx.x >> 5;
#pragma unroll
        for (int i = 0; i < 32; i += 8) {
            int c = c0 + ty + i, p = p0 + tx;
            if (p < P) tile[ty + i][tx] = s[(size_t)c * P + p];
        }
        __syncthreads();
#pragma unroll
        for (int i = 0; i < 32; i += 8) {
            int p = p0 + ty + i, c = c0 + tx;
            if (p < P) d[(size_t)p * C + c] = (f16)tile[tx][ty + i];
        }
    } else {
        // ---------------- corners part (cams cached in LDS) ----------------
        if (threadIdx.x < (unsigned)BV)
            make_cam(poses + (size_t)threadIdx.x * 5,
                     lds_cam + (size_t)threadIdx.x * 12);
        __syncthreads();   // convergent: before any bounds-check return

        int t = (bid - tgrid) * 256 + threadIdx.x;
        if (t >= B * N * 3) return;
        int point = t / 3;
        int v = t - point * 3;
        int b = point / N;

        float h0 = ((float)resolution[0] - 1.0f) * 0.5f;
        float h1 = ((float)resolution[1] - 1.0f) * 0.5f;
        float c_off0 = 111.5f - h0, c_off1 = 111.5f - h1;
        float inv_h0 = 1.0f / h0, inv_h1 = 1.0f / h1;

        const float* cm0 = lds_cam + (size_t)(b * 3) * 12;
        const float* cmv = lds_cam + (size_t)(b * 3 + v) * 12;

        const float* ip = inputs + (size_t)point * 3;
        const float px = ip[0], py = ip[1], pz = ip[2] - 0.8f;  // + MESH_POS

        const float wx = px * cm0[0] + py * cm0[3] + pz * cm0[6] + cm0[9];
        const float wy = px * cm0[1] + py * cm0[4] + pz * cm0[7] + cm0[10];
        const float wz = px * cm0[2] + py * cm0[5] + pz * cm0[8] + cm0[11];

        float qx = wx - cmv[9], qy = wy - cmv[10], qz = wz - cmv[11];
        float Xc = cmv[0] * qx + cmv[1] * qy + cmv[2] * qz;
        float Yc = cmv[3] * qx + cmv[4] * qy + cmv[5] * qz;
        float Zc = cmv[6] * qx + cmv[7] * qy + cmv[8] * qz;
        float invZ = 1.0f / Zc;
        float wpix = -248.0f * (Xc * invZ) + c_off0;
        float hpix =  248.0f * (Yc * invZ) + c_off1;
        float gx = fminf(fmaxf(wpix * inv_h0, -1.0f), 1.0f);
        float gy = fminf(fmaxf(hpix * inv_h1, -1.0f), 1.0f);

        unsigned* o = corn + (size_t)t * 12;
        const int S[3] = {56, 28, 14};
#pragma unroll
        for (int lvl = 0; lvl < 3; ++lvl) {
            Corners cr = mk_corners(gx, gy, S[lvl]);
            uint4 slot;
            slot.x = pack_u16(cr.p00, cr.p10);
            slot.y = pack_u16(cr.p01, cr.p11);
            slot.z = pack_f16(cr.w00, cr.w10);
            slot.w = pack_f16(cr.w01, cr.w11);
            *(uint4*)(o + lvl * 4) = slot;
        }
    }
}

template <int VEC> struct VecOf;
template <> struct VecOf<1> { using T = float; };
template <> struct VecOf<2> { using T = f32x2; };
template <> struct VecOf<4> { using T = f32x4; };
template <int VEC> struct F16VecOf;
template <> struct F16VecOf<1> { using T = f16; };
template <> struct F16VecOf<2> { using T = f16x2; };
template <> struct F16VecOf<4> { using T = f16x4; };

// packed-slot gather: u16 pixel idx << SHIFT = byte row offset; f16 weights.
template <int VEC, int SHIFT>
__device__ __forceinline__ typename VecOf<VEC>::T
gather4p(const f16* __restrict__ base, const uint4 pk, int lane) {
    using HV = typename F16VecOf<VEC>::T;
    using FV = typename VecOf<VEC>::T;
    const char* cb = (const char*)base;
    const int lo = lane * (VEC * 2);
    const int o00 = (int)((pk.x & 0xffffu) << SHIFT) + lo;
    const int o10 = (int)((pk.x >> 16) << SHIFT) + lo;
    const int o01 = (int)((pk.y & 0xffffu) << SHIFT) + lo;
    const int o11 = (int)((pk.y >> 16) << SHIFT) + lo;
    HV h00 = *(const HV*)(cb + o00);
    HV h10 = *(const HV*)(cb + o10);
    HV h01 = *(const HV*)(cb + o01);
    HV h11 = *(const HV*)(cb + o11);
    f16x2 wlo = __builtin_bit_cast(f16x2, pk.z);
    f16x2 whi = __builtin_bit_cast(f16x2, pk.w);
    const float w00 = (float)wlo.x, w10 = (float)wlo.y;
    const float w01 = (float)whi.x, w11 = (float)whi.y;
    FV a00, a10, a01, a11;
    if constexpr (VEC == 1) {
        a00 = (float)h00; a10 = (float)h10; a01 = (float)h01; a11 = (float)h11;
    } else {
        a00 = __builtin_convertvector(h00, FV);
        a10 = __builtin_convertvector(h10, FV);
        a01 = __builtin_convertvector(h01, FV);
        a11 = __builtin_convertvector(h11, FV);
    }
    return w00 * a00 + w10 * a10 + w01 * a01 + w11 * a11;
}

template <typename VecT, int VEC>
__device__ __forceinline__ void stats3(VecT a, VecT b, VecT c,
                                       VecT* omx, VecT* ome, VecT* osd) {
    const float* pa = (const float*)&a;
    const float* pb = (const float*)&b;
    const float* pc = (const float*)&c;
    float* qx = (float*)omx; float* qe = (float*)ome; float* qs = (float*)osd;
#pragma unroll
    for (int j = 0; j < VEC; ++j) {
        float x = pa[j], y = pb[j], z = pc[j];
        float m = fmaxf(x, fmaxf(y, z));
        float mean = (x + y + z) * (1.0f / 3.0f);
        float dx = x - mean, dy = y - mean, dz = z - mean;
        float s = sqrtf((dx * dx + dy * dy + dz * dz) * 0.5f);  // ddof=1
        qx[j] = m; qe[j] = mean; qs[j] = s;
    }
}

// Main kernel: 4 points/block, packed LDS staging (row r at r*1347), scalar
// b32 stats writes, sweep = aligned ds_read_b128 + nt store.
// b = blockIdx.x % B: XCD-batch pinning.
__global__ __launch_bounds__(256) void gproj_main_kernel(
    const f16* __restrict__ t0, const f16* __restrict__ t1,
    const f16* __restrict__ t2, const float* __restrict__ inputs,
    const unsigned* __restrict__ corn, float* __restrict__ out, int B, int N) {
    __shared__ alignas(16) float sb[4 * 1347];
    const int wave = threadIdx.x >> 6;
    const int lane = threadIdx.x & 63;
    const int b = blockIdx.x % B;
    const int pb = (blockIdx.x / B) * 4;
    const int pib = pb + wave;
    const bool valid = pib < N;

    if (valid) {
        const int point = b * N + pib;
        const int pu = __builtin_amdgcn_readfirstlane(point);
        const int bu = __builtin_amdgcn_readfirstlane(b);
        const float* ip = inputs + (size_t)point * 3;

        float  v0[3];
        f32x2  v1[3];
        f32x4  v2[3];

#pragma unroll
        for (int v = 0; v < 3; ++v) {
            const unsigned* cp = corn + (size_t)(pu * 3 + v) * 12;
            const int slice = v * B + bu;
            const f16* b0 = t0 + (size_t)slice * 64 * 3136;
            const f16* b1 = t1 + (size_t)slice * 128 * 784;
            const f16* b2 = t2 + (size_t)slice * 256 * 196;

            uint4 s0 = *(const uint4*)(cp);
            uint4 s1 = *(const uint4*)(cp + 4);
            uint4 s2 = *(const uint4*)(cp + 8);

            v0[v] = gather4p<1, 7>(b0, s0, lane);   // 64ch * 2B = 128B rows
            v1[v] = gather4p<2, 8>(b1, s1, lane);   // 256B rows
            v2[v] = gather4p<4, 9>(b2, s2, lane);   // 512B rows
        }

        float* row = sb + wave * 1347;   // packed: mirrors output row
        if (lane < 3) row[lane] = ip[lane];
        {   // level0: lane-stride 1
            float mx = fmaxf(v0[0], fmaxf(v0[1], v0[2]));
            float mean = (v0[0] + v0[1] + v0[2]) * (1.0f / 3.0f);
            float dx = v0[0] - mean, dy = v0[1] - mean, dz = v0[2] - mean;
            float sd = sqrtf((dx * dx + dy * dy + dz * dz) * 0.5f);
            row[3 + lane] = mx;
            row[451 + lane] = mean;
            row[899 + lane] = sd;
        }
        {   // level1: lane-stride 2 scalar b32 (free)
            f32x2 mx, me, sd;
            stats3<f32x2, 2>(v1[0], v1[1], v1[2], &mx, &me, &sd);
            const int g = 64 + 2 * lane;
            row[3 + g] = mx.x;   row[3 + g + 1] = mx.y;
            row[451 + g] = me.x; row[451 + g + 1] = me.y;
            row[899 + g] = sd.x; row[899 + g + 1] = sd.y;
        }
        {   // level2: lane-stride 4 scalar b32 (~1.58x, bounded)
            f32x4 mx, me, sd;
            stats3<f32x4, 4>(v2[0], v2[1], v2[2], &mx, &me, &sd);
            const int g = 192 + 4 * lane;
#pragma unroll
            for (int e = 0; e < 4; ++e) {
                row[3 + g + e] = mx[e];
                row[451 + g + e] = me[e];
                row[899 + g + e] = sd[e];
            }
        }
    }
    __syncthreads();

    // sweep: packed LDS == output region; aligned b128 reads, nt stores
    const int nvalid = min(N - pb, 4);
    const int len = nvalid * 1347;
    float* gout = out + (size_t)(b * N + pb) * 1347;
    const int len4 = len & ~3;
    for (int j = threadIdx.x * 4; j < len4; j += 1024) {
        f32x4 vv = *(const f32x4*)(sb + j);
        __builtin_nontemporal_store(vv, (f32x4*)(gout + j));
    }
    if ((len & 3) && threadIdx.x == 0) {
        for (int jj = len4; jj < len; ++jj) gout[jj] = sb[jj];
    }
}

// ---- mid-fallback: fused kernel (inline corners), f16 feats ----
template <int C, int VEC>
__device__ __forceinline__ typename VecOf<VEC>::T
samph(const f16* __restrict__ base, const Corners& cr, int lane) {
    using HV = typename F16VecOf<VEC>::T;
    using FV = typename VecOf<VEC>::T;
    const HV* r00 = (const HV*)(base + (size_t)cr.p00 * C);
    const HV* r10 = (const HV*)(base + (size_t)cr.p10 * C);
    const HV* r01 = (const HV*)(base + (size_t)cr.p01 * C);
    const HV* r11 = (const HV*)(base + (size_t)cr.p11 * C);
    HV h00 = r00[lane], h10 = r10[lane], h01 = r01[lane], h11 = r11[lane];
    FV a00, a10, a01, a11;
    if constexpr (VEC == 1) {
        a00 = (float)h00; a10 = (float)h10; a01 = (float)h01; a11 = (float)h11;
    } else {
        a00 = __builtin_convertvector(h00, FV);
        a10 = __builtin_convertvector(h10, FV);
        a01 = __builtin_convertvector(h01, FV);
        a11 = __builtin_convertvector(h11, FV);
    }
    return cr.w00 * a00 + cr.w10 * a10 + cr.w01 * a01 + cr.w11 * a11;
}

template <typename VecT, int VEC>
__device__ __forceinline__ void stats3_st(VecT a, VecT b, VecT c,
                                          float* pmx, float* pme, float* psd) {
    VecT mx, me, sd;
    stats3<VecT, VEC>(a, b, c, &mx, &me, &sd);
    *(VecT*)pmx = mx; *(VecT*)pme = me; *(VecT*)psd = sd;
}

__global__ __launch_bounds__(256) void gproj_fused_kernel(
    const f16* __restrict__ t0, const f16* __restrict__ t1,
    const f16* __restrict__ t2, const float* __restrict__ inputs,
    const float* __restrict__ cams, float* __restrict__ out, int B, int N) {
    const int wave = threadIdx.x >> 6;
    const int lane = threadIdx.x & 63;
    const int b = blockIdx.x % B;
    const int pib = (blockIdx.x / B) * 4 + wave;
    if (pib >= N) return;
    const int point = b * N + pib;

    const float c_off0 = cams[0], c_off1 = cams[1];
    const float inv_h0 = 1.0f / cams[2], inv_h1 = 1.0f / cams[3];
    const float* cam = cams + 4;

    const float* ip = inputs + (size_t)point * 3;
    const float px = ip[0], py = ip[1], pz = ip[2] - 0.8f;

    const float* m0 = cam + (size_t)(b * 3) * 12;
    const float wx = px * m0[0] + py * m0[3] + pz * m0[6] + m0[9];
    const float wy = px * m0[1] + py * m0[4] + pz * m0[7] + m0[10];
    const float wz = px * m0[2] + py * m0[5] + pz * m0[8] + m0[11];

    float  v0[3];
    f32x2  v1[3];
    f32x4  v2[3];

#pragma unroll
    for (int v = 0; v < 3; ++v) {
        const float* m = cam + (size_t)(b * 3 + v) * 12;
        float qx = wx - m[9], qy = wy - m[10], qz = wz - m[11];
        float Xc = m[0] * qx + m[1] * qy + m[2] * qz;
        float Yc = m[3] * qx + m[4] * qy + m[5] * qz;
        float Zc = m[6] * qx + m[7] * qy + m[8] * qz;
        float invZ = 1.0f / Zc;
        float wpix = -248.0f * (Xc * invZ) + c_off0;
        float hpix =  248.0f * (Yc * invZ) + c_off1;
        float gx = fminf(fmaxf(wpix * inv_h0, -1.0f), 1.0f);
        float gy = fminf(fmaxf(hpix * inv_h1, -1.0f), 1.0f);
        Corners cr0 = mk_corners(gx, gy, 56);
        Corners cr1 = mk_corners(gx, gy, 28);
        Corners cr2 = mk_corners(gx, gy, 14);
        const int slice = v * B + b;
        v0[v] = samph<64, 1>(t0 + (size_t)slice * 64 * 3136, cr0, lane);
        v1[v] = samph<128, 2>(t1 + (size_t)slice * 128 * 784, cr1, lane);
        v2[v] = samph<256, 4>(t2 + (size_t)slice * 256 * 196, cr2, lane);
    }

    float* op = out + (size_t)point * 1347;
    if (lane < 3) op[lane] = ip[lane];
    {
        float* basep = op + 3 + lane;
        float mx = fmaxf(v0[0], fmaxf(v0[1], v0[2]));
        float mean = (v0[0] + v0[1] + v0[2]) * (1.0f / 3.0f);
        float dx = v0[0] - mean, dy = v0[1] - mean, dz = v0[2] - mean;
        float sd = sqrtf((dx * dx + dy * dy + dz * dz) * 0.5f);
        basep[0] = mx; basep[448] = mean; basep[896] = sd;
    }
    {
        const int g = 64 + 2 * lane;
        stats3_st<f32x2, 2>(v1[0], v1[1], v1[2],
                            op + 3 + g, op + 451 + g, op + 899 + g);
    }
    {
        const int g = 192 + 4 * lane;
        stats3_st<f32x4, 4>(v2[0], v2[1], v2[2],
                            op + 3 + g, op + 451 + g, op + 899 + g);
    }
}

// ---- last-resort fallback (no workspace): channel-first f32 gathers ----
__device__ __forceinline__ float samp_cf(const float* __restrict__ base,
                                         const Corners& cr, int P, int c) {
    const float* bc = base + (size_t)c * P;
    return cr.w00 * bc[cr.p00] + cr.w10 * bc[cr.p10]
         + cr.w01 * bc[cr.p01] + cr.w11 * bc[cr.p11];
}

__global__ __launch_bounds__(256) void gproj_fallback_kernel(
    const float* __restrict__ f0, const float* __restrict__ f1,
    const float* __restrict__ f2, const float* __restrict__ inputs,
    const float* __restrict__ cams, float* __restrict__ out, int B, int N) {
    const int wave = threadIdx.x >> 6;
    const int lane = threadIdx.x & 63;
    const int point = blockIdx.x * 4 + wave;
    if (point >= B * N) return;
    const int b = point / N;

    const float c_off0 = cams[0], c_off1 = cams[1];
    const float inv_h0 = 1.0f / cams[2], inv_h1 = 1.0f / cams[3];
    const float* cam = cams + 4;

    const float* ip = inputs + (size_t)point * 3;
    const float px = ip[0], py = ip[1], pz = ip[2] - 0.8f;

    const float* m0 = cam + (size_t)(b * 3) * 12;
    const float wx = px * m0[0] + py * m0[3] + pz * m0[6] + m0[9];
    const float wy = px * m0[1] + py * m0[4] + pz * m0[7] + m0[10];
    const float wz = px * m0[2] + py * m0[5] + pz * m0[8] + m0[11];

    float vals[3][7];
#pragma unroll
    for (int v = 0; v < 3; ++v) {
        const float* m = cam + (size_t)(b * 3 + v) * 12;
        float qx = wx - m[9], qy = wy - m[10], qz = wz - m[11];
        float Xc = m[0] * qx + m[1] * qy + m[2] * qz;
        float Yc = m[3] * qx + m[4] * qy + m[5] * qz;
        float Zc = m[6] * qx + m[7] * qy + m[8] * qz;
        float invZ = 1.0f / Zc;
        float wpix = -248.0f * (Xc * invZ) + c_off0;
        float hpix =  248.0f * (Yc * invZ) + c_off1;
        float gx = fminf(fmaxf(wpix * inv_h0, -1.0f), 1.0f);
        float gy = fminf(fmaxf(hpix * inv_h1, -1.0f), 1.0f);
        Corners cr0 = mk_corners(gx, gy, 56);
        Corners cr1 = mk_corners(gx, gy, 28);
        Corners cr2 = mk_corners(gx, gy, 14);
        int slice = v * B + b;
        const float* b0 = f0 + (size_t)slice * 64 * 3136;
        const float* b1 = f1 + (size_t)slice * 128 * 784;
        const float* b2 = f2 + (size_t)slice * 256 * 196;
        vals[v][0] = samp_cf(b0, cr0, 3136, lane);
        vals[v][1] = samp_cf(b1, cr1, 784, lane);
        vals[v][2] = samp_cf(b1, cr1, 784, lane + 64);
        vals[v][3] = samp_cf(b2, cr2, 196, lane);
        vals[v][4] = samp_cf(b2, cr2, 196, lane + 64);
        vals[v][5] = samp_cf(b2, cr2, 196, lane + 128);
        vals[v][6] = samp_cf(b2, cr2, 196, lane + 192);
    }

    float* op = out + (size_t)point * 1347;
    if (lane < 3) op[lane] = ip[lane];
#pragma unroll
    for (int k = 0; k < 7; ++k) {
        float a = vals[0][k], bv = vals[1][k], cv = vals[2][k];
        float mx = fmaxf(a, fmaxf(bv, cv));
        float mean = (a + bv + cv) * (1.0f / 3.0f);
        float da = a - mean, db = bv - mean, dc = cv - mean;
        float sd = sqrtf((da * da + db * db + dc * dc) * 0.5f);
        int g = lane + 64 * k;
        op[3 + g] = mx;
        op[451 + g] = mean;
        op[899 + g] = sd;
    }
}

extern "C" void kernel_launch(void* const* d_in, const int* in_sizes, int n_in,
                              void* d_out, int out_size, void* d_ws, size_t ws_size,
                              hipStream_t stream) {
    const float* feat0 = (const float*)d_in[0];
    const float* feat1 = (const float*)d_in[1];
    const float* feat2 = (const float*)d_in[2];
    const float* inputs = (const float*)d_in[3];
    const float* poses = (const float*)d_in[4];
    const int* resolution = (const int*)d_in[5];
    float* out = (float*)d_out;
    float* ws = (float*)d_ws;

    const int V = 3;
    const int B = in_sizes[4] / (V * 5);
    const int N = in_sizes[3] / (B * 3);
    const int BV = B * V;
    const int total = B * N;

    const size_t cams_elems = 512;                     // f32
    const size_t t0_elems = (size_t)BV * 64 * 3136;    // f16
    const size_t t1_elems = (size_t)BV * 128 * 784;
    const size_t t2_elems = (size_t)BV * 256 * 196;
    const size_t th_elems = t0_elems + t1_elems + t2_elems;
    const size_t corn_elems = (size_t)total * 3 * 12;  // u32
    const size_t need_mid  = cams_elems * sizeof(float) + th_elems * sizeof(f16);
    const size_t need_full = need_mid + corn_elems * sizeof(unsigned);

    const int nbb = (N + 3) / 4;   // blocks per batch
    const int tgrid = BV * (98 * 2 + 25 * 4 + 7 * 8);

    if (ws_size >= need_full) {
        unsigned* corn = (unsigned*)(ws + cams_elems);
        f16* t0 = (f16*)(corn + corn_elems);
        f16* t1 = t0 + t0_elems;
        f16* t2 = t1 + t1_elems;
        const int cgrid = (total * 3 + 255) / 256;
        prep_kernel<<<tgrid + cgrid, 256, 0, stream>>>(
            feat0, feat1, feat2, t0, t1, t2, inputs, poses, resolution,
            corn, B, N, BV, tgrid);
        gproj_main_kernel<<<B * nbb, 256, 0, stream>>>(t0, t1, t2, inputs, corn, out, B, N);
    } else if (ws_size >= need_mid) {
        setup_cams_kernel<<<1, 64, 0, stream>>>(poses, resolution, ws, BV);
        f16* t0 = (f16*)(ws + cams_elems);
        f16* t1 = t0 + t0_elems;
        f16* t2 = t1 + t1_elems;
        prep_kernel<<<tgrid, 256, 0, stream>>>(
            feat0, feat1, feat2, t0, t1, t2, inputs, poses, resolution,
            /*corn=*/(unsigned*)ws, B, N, BV, tgrid);
        gproj_fused_kernel<<<B * nbb, 256, 0, stream>>>(t0, t1, t2, inputs, ws, out, B, N);
    } else {
        setup_cams_kernel<<<1, 64, 0, stream>>>(poses, resolution, ws, BV);
        gproj_fallback_kernel<<<(total + 3) / 4, 256, 0, stream>>>(
            feat0, feat1, feat2, inputs, ws, out, B, N);
    }
}

// Round 11
// 86.593 us; speedup vs baseline: 2.6605x; 1.0178x over previous
//
#include <hip/hip_runtime.h>
#include <cstdint>
#include <cmath>

// ---------------------------------------------------------------------------
// GProjection: project B*N points into V=3 views, bilinear-sample 3 feature
// pyramids (64@56x56, 128@28x28, 256@14x14 -> 448 ch), reduce max/mean/std
// over views. Output [B,N,3+3*448] f32.
//
// R11:
//  - main: all 9 corn slots (144B wave-uniform) s_loaded up front -> all 36
//    gather addresses ready after one scalar-load wait (max MLP).
//  - prep transpose: f16x2 channel-pair writes (half the store instrs,
//    256B/wave-instruction).
// Carried: packed 16B corn slots + LDS-cam prep (R10), packed-LDS staging +
// aligned b128 sweep (R9), prep union kernel (R8), LDS-staged stats (R7),
// corners precompute (R5), f16 channel-last feats (R3), XCD-batch pinning +
// nt stores (R2).
// ---------------------------------------------------------------------------

typedef float f32x2 __attribute__((ext_vector_type(2)));
typedef float f32x4 __attribute__((ext_vector_type(4)));
typedef _Float16 f16;
typedef _Float16 f16x2 __attribute__((ext_vector_type(2)));
typedef _Float16 f16x4 __attribute__((ext_vector_type(4)));

// ---- camera matrix from a pose row ----
__device__ __forceinline__ void make_cam(const float* __restrict__ p, float* c) {
    const float d = 0.017453292519943295f;  // pi/180
    float theta = p[0] * d;
    float elr   = p[1] * d;
    float dist  = p[3];
    float st = sinf(theta), ct = cosf(theta);
    float se = sinf(elr),   ce = cosf(elr);
    float camy = dist * se;
    float lens = dist * ce;
    float camx = lens * ct;
    float camz = lens * st;
    float Zx = camx, Zy = camy, Zz = camz;
    float Yx = -camy * ct, Yy = lens, Yz = -camy * st;  // cos/sin(theta+pi)
    float Xx = Yy * Zz - Yz * Zy;
    float Xy = Yz * Zx - Yx * Zz;
    float Xz = Yx * Zy - Yy * Zx;
    float rx = 1.0f / sqrtf(Xx*Xx + Xy*Xy + Xz*Xz);
    float ry = 1.0f / sqrtf(Yx*Yx + Yy*Yy + Yz*Yz);
    float rz = 1.0f / sqrtf(Zx*Zx + Zy*Zy + Zz*Zz);
    c[0] = Xx*rx; c[1] = Xy*rx; c[2] = Xz*rx;
    c[3] = Yx*ry; c[4] = Yy*ry; c[5] = Yz*ry;
    c[6] = Zx*rz; c[7] = Zy*rz; c[8] = Zz*rz;
    c[9] = camx; c[10] = camy; c[11] = camz;
}

__global__ void setup_cams_kernel(const float* __restrict__ poses,
                                  const int* __restrict__ resolution,
                                  float* __restrict__ ws, int BV) {
    int t = blockIdx.x * blockDim.x + threadIdx.x;
    if (t == 0) {
        float h0 = ((float)resolution[0] - 1.0f) * 0.5f;
        float h1 = ((float)resolution[1] - 1.0f) * 0.5f;
        ws[0] = 111.5f - h0;   // c_off0
        ws[1] = 111.5f - h1;   // c_off1
        ws[2] = h0;            // half_res0
        ws[3] = h1;            // half_res1
    }
    if (t < BV) make_cam(poses + (size_t)t * 5, ws + 4 + (size_t)t * 12);
}

struct Corners {
    int p00, p10, p01, p11;
    float w00, w10, w01, w11;
};

__device__ __forceinline__ Corners mk_corners(float gx, float gy, int S) {
    // torch grid_sample: bilinear, zeros padding, align_corners=False
    float x = ((gx + 1.0f) * (float)S - 1.0f) * 0.5f;
    float y = ((gy + 1.0f) * (float)S - 1.0f) * 0.5f;
    float x0f = floorf(x), y0f = floorf(y);
    float wx1 = x - x0f, wy1 = y - y0f;
    float wx0 = 1.0f - wx1, wy0 = 1.0f - wy1;
    int x0 = (int)x0f, y0 = (int)y0f;
    int x1 = x0 + 1, y1 = y0 + 1;
    bool vx0 = (x0 >= 0) && (x0 <= S - 1);
    bool vx1 = (x1 >= 0) && (x1 <= S - 1);
    bool vy0 = (y0 >= 0) && (y0 <= S - 1);
    bool vy1 = (y1 >= 0) && (y1 <= S - 1);
    int xi0 = min(max(x0, 0), S - 1);
    int xi1 = min(max(x1, 0), S - 1);
    int yi0 = min(max(y0, 0), S - 1);
    int yi1 = min(max(y1, 0), S - 1);
    Corners c;
    c.p00 = yi0 * S + xi0;
    c.p10 = yi0 * S + xi1;
    c.p01 = yi1 * S + xi0;
    c.p11 = yi1 * S + xi1;
    c.w00 = wx0 * wy0 * ((vx0 && vy0) ? 1.0f : 0.0f);
    c.w10 = wx1 * wy0 * ((vx1 && vy0) ? 1.0f : 0.0f);
    c.w01 = wx0 * wy1 * ((vx0 && vy1) ? 1.0f : 0.0f);
    c.w11 = wx1 * wy1 * ((vx1 && vy1) ? 1.0f : 0.0f);
    return c;
}

__device__ __forceinline__ unsigned pack_u16(int a, int b) {
    return (unsigned)(a & 0xffff) | ((unsigned)b << 16);
}
__device__ __forceinline__ unsigned pack_f16(float a, float b) {
    f16x2 h; h.x = (f16)a; h.y = (f16)b;
    return __builtin_bit_cast(unsigned, h);
}

// ---- prep kernel: transpose tiles UNION corner blocks, one dispatch ----
// corn slot layout per (point,view): 3 x uint4 {o00|o10<<16, o01|o11<<16,
// h2(w00,w10), h2(w01,w11)} -> 48B.
__global__ __launch_bounds__(256) void prep_kernel(
    const float* __restrict__ f0, const float* __restrict__ f1,
    const float* __restrict__ f2, f16* __restrict__ t0, f16* __restrict__ t1,
    f16* __restrict__ t2, const float* __restrict__ inputs,
    const float* __restrict__ poses, const int* __restrict__ resolution,
    unsigned* __restrict__ corn, int B, int N, int BV, int tgrid) {
    __shared__ float tile[32][33];
    __shared__ float lds_cam[24 * 12];
    const int bid = blockIdx.x;
    if (bid < tgrid) {
        // ---------------- transpose part ----------------
        const int nb0 = 98 * 2 * BV;
        const int nb1 = 25 * 4 * BV;
        const float* src; f16* dst; int C, P, tP, local;
        if (bid < nb0)            { src = f0; dst = t0; C = 64;  P = 3136; tP = 98; local = bid; }
        else if (bid < nb0 + nb1) { src = f1; dst = t1; C = 128; P = 784;  tP = 25; local = bid - nb0; }
        else                      { src = f2; dst = t2; C = 256; P = 196;  tP = 7;  local = bid - nb0 - nb1; }
        int per = tP * (C >> 5);
        int slice = local / per;
        int rem = local - slice * per;
        int cy = rem / tP;
        int cx = rem - cy * tP;
        const float* s = src + (size_t)slice * C * P;
        f16* d = dst + (size_t)slice * C * P;
        int p0 = cx * 32, c0 = cy * 32;
        int tx = threadIdx.x & 31, ty = threadIdx.x >> 5;  // 32 x 8
#pragma unroll
        for (int i = 0; i < 32; i += 8) {
            int c = c0 + ty + i, p = p0 + tx;
            if (p < P) tile[ty + i][tx] = s[(size_t)c * P + p];   // tile[c_l][p_l]
        }
        __syncthreads();
        // f16x2 channel-pair writes: 16 c-pairs x 16 p-rows per pass, 2 passes
        int txp = threadIdx.x & 15;   // c-pair index
        int typ = threadIdx.x >> 4;   // p-row 0..15
#pragma unroll
        for (int i = 0; i < 32; i += 16) {
            int p = p0 + typ + i;
            int c = c0 + 2 * txp;
            if (p < P) {
                f16x2 h;
                h.x = (f16)tile[2 * txp][typ + i];
                h.y = (f16)tile[2 * txp + 1][typ + i];
                *(f16x2*)(d + (size_t)p * C + c) = h;
            }
        }
    } else {
        // ---------------- corners part (cams cached in LDS) ----------------
        if (threadIdx.x < (unsigned)BV)
            make_cam(poses + (size_t)threadIdx.x * 5,
                     lds_cam + (size_t)threadIdx.x * 12);
        __syncthreads();   // convergent: before any bounds-check return

        int t = (bid - tgrid) * 256 + threadIdx.x;
        if (t >= B * N * 3) return;
        int point = t / 3;
        int v = t - point * 3;
        int b = point / N;

        float h0 = ((float)resolution[0] - 1.0f) * 0.5f;
        float h1 = ((float)resolution[1] - 1.0f) * 0.5f;
        float c_off0 = 111.5f - h0, c_off1 = 111.5f - h1;
        float inv_h0 = 1.0f / h0, inv_h1 = 1.0f / h1;

        const float* cm0 = lds_cam + (size_t)(b * 3) * 12;
        const float* cmv = lds_cam + (size_t)(b * 3 + v) * 12;

        const float* ip = inputs + (size_t)point * 3;
        const float px = ip[0], py = ip[1], pz = ip[2] - 0.8f;  // + MESH_POS

        const float wx = px * cm0[0] + py * cm0[3] + pz * cm0[6] + cm0[9];
        const float wy = px * cm0[1] + py * cm0[4] + pz * cm0[7] + cm0[10];
        const float wz = px * cm0[2] + py * cm0[5] + pz * cm0[8] + cm0[11];

        float qx = wx - cmv[9], qy = wy - cmv[10], qz = wz - cmv[11];
        float Xc = cmv[0] * qx + cmv[1] * qy + cmv[2] * qz;
        float Yc = cmv[3] * qx + cmv[4] * qy + cmv[5] * qz;
        float Zc = cmv[6] * qx + cmv[7] * qy + cmv[8] * qz;
        float invZ = 1.0f / Zc;
        float wpix = -248.0f * (Xc * invZ) + c_off0;
        float hpix =  248.0f * (Yc * invZ) + c_off1;
        float gx = fminf(fmaxf(wpix * inv_h0, -1.0f), 1.0f);
        float gy = fminf(fmaxf(hpix * inv_h1, -1.0f), 1.0f);

        unsigned* o = corn + (size_t)t * 12;
        const int S[3] = {56, 28, 14};
#pragma unroll
        for (int lvl = 0; lvl < 3; ++lvl) {
            Corners cr = mk_corners(gx, gy, S[lvl]);
            uint4 slot;
            slot.x = pack_u16(cr.p00, cr.p10);
            slot.y = pack_u16(cr.p01, cr.p11);
            slot.z = pack_f16(cr.w00, cr.w10);
            slot.w = pack_f16(cr.w01, cr.w11);
            *(uint4*)(o + lvl * 4) = slot;
        }
    }
}

template <int VEC> struct VecOf;
template <> struct VecOf<1> { using T = float; };
template <> struct VecOf<2> { using T = f32x2; };
template <> struct VecOf<4> { using T = f32x4; };
template <int VEC> struct F16VecOf;
template <> struct F16VecOf<1> { using T = f16; };
template <> struct F16VecOf<2> { using T = f16x2; };
template <> struct F16VecOf<4> { using T = f16x4; };

// packed-slot gather: u16 pixel idx << SHIFT = byte row offset; f16 weights.
template <int VEC, int SHIFT>
__device__ __forceinline__ typename VecOf<VEC>::T
gather4p(const f16* __restrict__ base, const uint4 pk, int lane) {
    using HV = typename F16VecOf<VEC>::T;
    using FV = typename VecOf<VEC>::T;
    const char* cb = (const char*)base;
    const int lo = lane * (VEC * 2);
    const int o00 = (int)((pk.x & 0xffffu) << SHIFT) + lo;
    const int o10 = (int)((pk.x >> 16) << SHIFT) + lo;
    const int o01 = (int)((pk.y & 0xffffu) << SHIFT) + lo;
    const int o11 = (int)((pk.y >> 16) << SHIFT) + lo;
    HV h00 = *(const HV*)(cb + o00);
    HV h10 = *(const HV*)(cb + o10);
    HV h01 = *(const HV*)(cb + o01);
    HV h11 = *(const HV*)(cb + o11);
    f16x2 wlo = __builtin_bit_cast(f16x2, pk.z);
    f16x2 whi = __builtin_bit_cast(f16x2, pk.w);
    const float w00 = (float)wlo.x, w10 = (float)wlo.y;
    const float w01 = (float)whi.x, w11 = (float)whi.y;
    FV a00, a10, a01, a11;
    if constexpr (VEC == 1) {
        a00 = (float)h00; a10 = (float)h10; a01 = (float)h01; a11 = (float)h11;
    } else {
        a00 = __builtin_convertvector(h00, FV);
        a10 = __builtin_convertvector(h10, FV);
        a01 = __builtin_convertvector(h01, FV);
        a11 = __builtin_convertvector(h11, FV);
    }
    return w00 * a00 + w10 * a10 + w01 * a01 + w11 * a11;
}

template <typename VecT, int VEC>
__device__ __forceinline__ void stats3(VecT a, VecT b, VecT c,
                                       VecT* omx, VecT* ome, VecT* osd) {
    const float* pa = (const float*)&a;
    const float* pb = (const float*)&b;
    const float* pc = (const float*)&c;
    float* qx = (float*)omx; float* qe = (float*)ome; float* qs = (float*)osd;
#pragma unroll
    for (int j = 0; j < VEC; ++j) {
        float x = pa[j], y = pb[j], z = pc[j];
        float m = fmaxf(x, fmaxf(y, z));
        float mean = (x + y + z) * (1.0f / 3.0f);
        float dx = x - mean, dy = y - mean, dz = z - mean;
        float s = sqrtf((dx * dx + dy * dy + dz * dz) * 0.5f);  // ddof=1
        qx[j] = m; qe[j] = mean; qs[j] = s;
    }
}

// Main kernel: 4 points/block, packed LDS staging (row r at r*1347), scalar
// b32 stats writes, sweep = aligned ds_read_b128 + nt store.
// b = blockIdx.x % B: XCD-batch pinning.
__global__ __launch_bounds__(256) void gproj_main_kernel(
    const f16* __restrict__ t0, const f16* __restrict__ t1,
    const f16* __restrict__ t2, const float* __restrict__ inputs,
    const unsigned* __restrict__ corn, float* __restrict__ out, int B, int N) {
    __shared__ alignas(16) float sb[4 * 1347];
    const int wave = threadIdx.x >> 6;
    const int lane = threadIdx.x & 63;
    const int b = blockIdx.x % B;
    const int pb = (blockIdx.x / B) * 4;
    const int pib = pb + wave;
    const bool valid = pib < N;

    if (valid) {
        const int point = b * N + pib;
        const int pu = __builtin_amdgcn_readfirstlane(point);
        const int bu = __builtin_amdgcn_readfirstlane(b);
        const float* ip = inputs + (size_t)point * 3;

        // hoist ALL 9 corn slots (144B wave-uniform) before any gather:
        // one scalar-load wait exposes all 36 gather addresses.
        uint4 sl[9];
        const unsigned* cpb = corn + (size_t)(pu * 3) * 12;
#pragma unroll
        for (int k = 0; k < 9; ++k) sl[k] = *(const uint4*)(cpb + k * 4);

        float  v0[3];
        f32x2  v1[3];
        f32x4  v2[3];

#pragma unroll
        for (int v = 0; v < 3; ++v) {
            const int slice = v * B + bu;
            const f16* b0 = t0 + (size_t)slice * 64 * 3136;
            const f16* b1 = t1 + (size_t)slice * 128 * 784;
            const f16* b2 = t2 + (size_t)slice * 256 * 196;
            v0[v] = gather4p<1, 7>(b0, sl[v * 3 + 0], lane);  // 128B rows
            v1[v] = gather4p<2, 8>(b1, sl[v * 3 + 1], lane);  // 256B rows
            v2[v] = gather4p<4, 9>(b2, sl[v * 3 + 2], lane);  // 512B rows
        }

        float* row = sb + wave * 1347;   // packed: mirrors output row
        if (lane < 3) row[lane] = ip[lane];
        {   // level0: lane-stride 1
            float mx = fmaxf(v0[0], fmaxf(v0[1], v0[2]));
            float mean = (v0[0] + v0[1] + v0[2]) * (1.0f / 3.0f);
            float dx = v0[0] - mean, dy = v0[1] - mean, dz = v0[2] - mean;
            float sd = sqrtf((dx * dx + dy * dy + dz * dz) * 0.5f);
            row[3 + lane] = mx;
            row[451 + lane] = mean;
            row[899 + lane] = sd;
        }
        {   // level1: lane-stride 2 scalar b32 (free)
            f32x2 mx, me, sd;
            stats3<f32x2, 2>(v1[0], v1[1], v1[2], &mx, &me, &sd);
            const int g = 64 + 2 * lane;
            row[3 + g] = mx.x;   row[3 + g + 1] = mx.y;
            row[451 + g] = me.x; row[451 + g + 1] = me.y;
            row[899 + g] = sd.x; row[899 + g + 1] = sd.y;
        }
        {   // level2: lane-stride 4 scalar b32 (~1.58x, bounded)
            f32x4 mx, me, sd;
            stats3<f32x4, 4>(v2[0], v2[1], v2[2], &mx, &me, &sd);
            const int g = 192 + 4 * lane;
#pragma unroll
            for (int e = 0; e < 4; ++e) {
                row[3 + g + e] = mx[e];
                row[451 + g + e] = me[e];
                row[899 + g + e] = sd[e];
            }
        }
    }
    __syncthreads();

    // sweep: packed LDS == output region; aligned b128 reads, nt stores
    const int nvalid = min(N - pb, 4);
    const int len = nvalid * 1347;
    float* gout = out + (size_t)(b * N + pb) * 1347;
    const int len4 = len & ~3;
    for (int j = threadIdx.x * 4; j < len4; j += 1024) {
        f32x4 vv = *(const f32x4*)(sb + j);
        __builtin_nontemporal_store(vv, (f32x4*)(gout + j));
    }
    if ((len & 3) && threadIdx.x == 0) {
        for (int jj = len4; jj < len; ++jj) gout[jj] = sb[jj];
    }
}

// ---- mid-fallback: fused kernel (inline corners), f16 feats ----
template <int C, int VEC>
__device__ __forceinline__ typename VecOf<VEC>::T
samph(const f16* __restrict__ base, const Corners& cr, int lane) {
    using HV = typename F16VecOf<VEC>::T;
    using FV = typename VecOf<VEC>::T;
    const HV* r00 = (const HV*)(base + (size_t)cr.p00 * C);
    const HV* r10 = (const HV*)(base + (size_t)cr.p10 * C);
    const HV* r01 = (const HV*)(base + (size_t)cr.p01 * C);
    const HV* r11 = (const HV*)(base + (size_t)cr.p11 * C);
    HV h00 = r00[lane], h10 = r10[lane], h01 = r01[lane], h11 = r11[lane];
    FV a00, a10, a01, a11;
    if constexpr (VEC == 1) {
        a00 = (float)h00; a10 = (float)h10; a01 = (float)h01; a11 = (float)h11;
    } else {
        a00 = __builtin_convertvector(h00, FV);
        a10 = __builtin_convertvector(h10, FV);
        a01 = __builtin_convertvector(h01, FV);
        a11 = __builtin_convertvector(h11, FV);
    }
    return cr.w00 * a00 + cr.w10 * a10 + cr.w01 * a01 + cr.w11 * a11;
}

template <typename VecT, int VEC>
__device__ __forceinline__ void stats3_st(VecT a, VecT b, VecT c,
                                          float* pmx, float* pme, float* psd) {
    VecT mx, me, sd;
    stats3<VecT, VEC>(a, b, c, &mx, &me, &sd);
    *(VecT*)pmx = mx; *(VecT*)pme = me; *(VecT*)psd = sd;
}

__global__ __launch_bounds__(256) void gproj_fused_kernel(
    const f16* __restrict__ t0, const f16* __restrict__ t1,
    const f16* __restrict__ t2, const float* __restrict__ inputs,
    const float* __restrict__ cams, float* __restrict__ out, int B, int N) {
    const int wave = threadIdx.x >> 6;
    const int lane = threadIdx.x & 63;
    const int b = blockIdx.x % B;
    const int pib = (blockIdx.x / B) * 4 + wave;
    if (pib >= N) return;
    const int point = b * N + pib;

    const float c_off0 = cams[0], c_off1 = cams[1];
    const float inv_h0 = 1.0f / cams[2], inv_h1 = 1.0f / cams[3];
    const float* cam = cams + 4;

    const float* ip = inputs + (size_t)point * 3;
    const float px = ip[0], py = ip[1], pz = ip[2] - 0.8f;

    const float* m0 = cam + (size_t)(b * 3) * 12;
    const float wx = px * m0[0] + py * m0[3] + pz * m0[6] + m0[9];
    const float wy = px * m0[1] + py * m0[4] + pz * m0[7] + m0[10];
    const float wz = px * m0[2] + py * m0[5] + pz * m0[8] + m0[11];

    float  v0[3];
    f32x2  v1[3];
    f32x4  v2[3];

#pragma unroll
    for (int v = 0; v < 3; ++v) {
        const float* m = cam + (size_t)(b * 3 + v) * 12;
        float qx = wx - m[9], qy = wy - m[10], qz = wz - m[11];
        float Xc = m[0] * qx + m[1] * qy + m[2] * qz;
        float Yc = m[3] * qx + m[4] * qy + m[5] * qz;
        float Zc = m[6] * qx + m[7] * qy + m[8] * qz;
        float invZ = 1.0f / Zc;
        float wpix = -248.0f * (Xc * invZ) + c_off0;
        float hpix =  248.0f * (Yc * invZ) + c_off1;
        float gx = fminf(fmaxf(wpix * inv_h0, -1.0f), 1.0f);
        float gy = fminf(fmaxf(hpix * inv_h1, -1.0f), 1.0f);
        Corners cr0 = mk_corners(gx, gy, 56);
        Corners cr1 = mk_corners(gx, gy, 28);
        Corners cr2 = mk_corners(gx, gy, 14);
        const int slice = v * B + b;
        v0[v] = samph<64, 1>(t0 + (size_t)slice * 64 * 3136, cr0, lane);
        v1[v] = samph<128, 2>(t1 + (size_t)slice * 128 * 784, cr1, lane);
        v2[v] = samph<256, 4>(t2 + (size_t)slice * 256 * 196, cr2, lane);
    }

    float* op = out + (size_t)point * 1347;
    if (lane < 3) op[lane] = ip[lane];
    {
        float* basep = op + 3 + lane;
        float mx = fmaxf(v0[0], fmaxf(v0[1], v0[2]));
        float mean = (v0[0] + v0[1] + v0[2]) * (1.0f / 3.0f);
        float dx = v0[0] - mean, dy = v0[1] - mean, dz = v0[2] - mean;
        float sd = sqrtf((dx * dx + dy * dy + dz * dz) * 0.5f);
        basep[0] = mx; basep[448] = mean; basep[896] = sd;
    }
    {
        const int g = 64 + 2 * lane;
        stats3_st<f32x2, 2>(v1[0], v1[1], v1[2],
                            op + 3 + g, op + 451 + g, op + 899 + g);
    }
    {
        const int g = 192 + 4 * lane;
        stats3_st<f32x4, 4>(v2[0], v2[1], v2[2],
                            op + 3 + g, op + 451 + g, op + 899 + g);
    }
}

// ---- last-resort fallback (no workspace): channel-first f32 gathers ----
__device__ __forceinline__ float samp_cf(const float* __restrict__ base,
                                         const Corners& cr, int P, int c) {
    const float* bc = base + (size_t)c * P;
    return cr.w00 * bc[cr.p00] + cr.w10 * bc[cr.p10]
         + cr.w01 * bc[cr.p01] + cr.w11 * bc[cr.p11];
}

__global__ __launch_bounds__(256) void gproj_fallback_kernel(
    const float* __restrict__ f0, const float* __restrict__ f1,
    const float* __restrict__ f2, const float* __restrict__ inputs,
    const float* __restrict__ cams, float* __restrict__ out, int B, int N) {
    const int wave = threadIdx.x >> 6;
    const int lane = threadIdx.x & 63;
    const int point = blockIdx.x * 4 + wave;
    if (point >= B * N) return;
    const int b = point / N;

    const float c_off0 = cams[0], c_off1 = cams[1];
    const float inv_h0 = 1.0f / cams[2], inv_h1 = 1.0f / cams[3];
    const float* cam = cams + 4;

    const float* ip = inputs + (size_t)point * 3;
    const float px = ip[0], py = ip[1], pz = ip[2] - 0.8f;

    const float* m0 = cam + (size_t)(b * 3) * 12;
    const float wx = px * m0[0] + py * m0[3] + pz * m0[6] + m0[9];
    const float wy = px * m0[1] + py * m0[4] + pz * m0[7] + m0[10];
    const float wz = px * m0[2] + py * m0[5] + pz * m0[8] + m0[11];

    float vals[3][7];
#pragma unroll
    for (int v = 0; v < 3; ++v) {
        const float* m = cam + (size_t)(b * 3 + v) * 12;
        float qx = wx - m[9], qy = wy - m[10], qz = wz - m[11];
        float Xc = m[0] * qx + m[1] * qy + m[2] * qz;
        float Yc = m[3] * qx + m[4] * qy + m[5] * qz;
        float Zc = m[6] * qx + m[7] * qy + m[8] * qz;
        float invZ = 1.0f / Zc;
        float wpix = -248.0f * (Xc * invZ) + c_off0;
        float hpix =  248.0f * (Yc * invZ) + c_off1;
        float gx = fminf(fmaxf(wpix * inv_h0, -1.0f), 1.0f);
        float gy = fminf(fmaxf(hpix * inv_h1, -1.0f), 1.0f);
        Corners cr0 = mk_corners(gx, gy, 56);
        Corners cr1 = mk_corners(gx, gy, 28);
        Corners cr2 = mk_corners(gx, gy, 14);
        int slice = v * B + b;
        const float* b0 = f0 + (size_t)slice * 64 * 3136;
        const float* b1 = f1 + (size_t)slice * 128 * 784;
        const float* b2 = f2 + (size_t)slice * 256 * 196;
        vals[v][0] = samp_cf(b0, cr0, 3136, lane);
        vals[v][1] = samp_cf(b1, cr1, 784, lane);
        vals[v][2] = samp_cf(b1, cr1, 784, lane + 64);
        vals[v][3] = samp_cf(b2, cr2, 196, lane);
        vals[v][4] = samp_cf(b2, cr2, 196, lane + 64);
        vals[v][5] = samp_cf(b2, cr2, 196, lane + 128);
        vals[v][6] = samp_cf(b2, cr2, 196, lane + 192);
    }

    float* op = out + (size_t)point * 1347;
    if (lane < 3) op[lane] = ip[lane];
#pragma unroll
    for (int k = 0; k < 7; ++k) {
        float a = vals[0][k], bv = vals[1][k], cv = vals[2][k];
        float mx = fmaxf(a, fmaxf(bv, cv));
        float mean = (a + bv + cv) * (1.0f / 3.0f);
        float da = a - mean, db = bv - mean, dc = cv - mean;
        float sd = sqrtf((da * da + db * db + dc * dc) * 0.5f);
        int g = lane + 64 * k;
        op[3 + g] = mx;
        op[451 + g] = mean;
        op[899 + g] = sd;
    }
}

extern "C" void kernel_launch(void* const* d_in, const int* in_sizes, int n_in,
                              void* d_out, int out_size, void* d_ws, size_t ws_size,
                              hipStream_t stream) {
    const float* feat0 = (const float*)d_in[0];
    const float* feat1 = (const float*)d_in[1];
    const float* feat2 = (const float*)d_in[2];
    const float* inputs = (const float*)d_in[3];
    const float* poses = (const float*)d_in[4];
    const int* resolution = (const int*)d_in[5];
    float* out = (float*)d_out;
    float* ws = (float*)d_ws;

    const int V = 3;
    const int B = in_sizes[4] / (V * 5);
    const int N = in_sizes[3] / (B * 3);
    const int BV = B * V;
    const int total = B * N;

    const size_t cams_elems = 512;                     // f32
    const size_t t0_elems = (size_t)BV * 64 * 3136;    // f16
    const size_t t1_elems = (size_t)BV * 128 * 784;
    const size_t t2_elems = (size_t)BV * 256 * 196;
    const size_t th_elems = t0_elems + t1_elems + t2_elems;
    const size_t corn_elems = (size_t)total * 3 * 12;  // u32
    const size_t need_mid  = cams_elems * sizeof(float) + th_elems * sizeof(f16);
    const size_t need_full = need_mid + corn_elems * sizeof(unsigned);

    const int nbb = (N + 3) / 4;   // blocks per batch
    const int tgrid = BV * (98 * 2 + 25 * 4 + 7 * 8);

    if (ws_size >= need_full) {
        unsigned* corn = (unsigned*)(ws + cams_elems);
        f16* t0 = (f16*)(corn + corn_elems);
        f16* t1 = t0 + t0_elems;
        f16* t2 = t1 + t1_elems;
        const int cgrid = (total * 3 + 255) / 256;
        prep_kernel<<<tgrid + cgrid, 256, 0, stream>>>(
            feat0, feat1, feat2, t0, t1, t2, inputs, poses, resolution,
            corn, B, N, BV, tgrid);
        gproj_main_kernel<<<B * nbb, 256, 0, stream>>>(t0, t1, t2, inputs, corn, out, B, N);
    } else if (ws_size >= need_mid) {
        setup_cams_kernel<<<1, 64, 0, stream>>>(poses, resolution, ws, BV);
        f16* t0 = (f16*)(ws + cams_elems);
        f16* t1 = t0 + t0_elems;
        f16* t2 = t1 + t1_elems;
        prep_kernel<<<tgrid, 256, 0, stream>>>(
            feat0, feat1, feat2, t0, t1, t2, inputs, poses, resolution,
            /*corn=*/(unsigned*)ws, B, N, BV, tgrid);
        gproj_fused_kernel<<<B * nbb, 256, 0, stream>>>(t0, t1, t2, inputs, ws, out, B, N);
    } else {
        setup_cams_kernel<<<1, 64, 0, stream>>>(poses, resolution, ws, BV);
        gproj_fallback_kernel<<<(total + 3) / 4, 256, 0, stream>>>(
            feat0, feat1, feat2, inputs, ws, out, B, N);
    }
}